// Round 16
// baseline (297.533 us; speedup 1.0000x reference)
//
#include <hip/hip_runtime.h>
#include <cstddef>

namespace {

constexpr int kB   = 8;
constexpr int kNQ  = 900;
constexpr int kD   = 256;
constexpr int kDFF = 1024;
constexpr int kLV  = 13294;

typedef short bf16x8 __attribute__((ext_vector_type(8)));
typedef float f32x4  __attribute__((ext_vector_type(4)));

__device__ inline unsigned short f2bf(float f) {
  union { float f; unsigned u; } v; v.f = f;
  return (unsigned short)((v.u + 0x7FFF + ((v.u >> 16) & 1)) >> 16);
}

__device__ inline float bf2f(unsigned short u) {
  union { unsigned u; float f; } v; v.u = (unsigned)u << 16;
  return v.f;
}

// HW packed f32->bf16 (RNE)
__device__ inline unsigned cvt_pk_bf16(float a, float b) {
  unsigned r;
  asm("v_cvt_pk_bf16_f32 %0, %1, %2" : "=v"(r) : "v"(a), "v"(b));
  return r;
}

// ---------------------------------------------------------------------------
// Streaming f32 -> bf16 convert (8 floats / thread / iter).
// ---------------------------------------------------------------------------
__global__ __launch_bounds__(256) void f32_to_bf16_kernel(
    const float* __restrict__ in, unsigned* __restrict__ out, int n8) {
  int i = blockIdx.x * 256 + threadIdx.x;
  const int stride = gridDim.x * 256;
  for (; i < n8; i += stride) {
    const float4 a = ((const float4*)in)[(size_t)i * 2];
    const float4 b = ((const float4*)in)[(size_t)i * 2 + 1];
    uint4 r;
    r.x = cvt_pk_bf16(a.x, a.y);
    r.y = cvt_pk_bf16(a.z, a.w);
    r.z = cvt_pk_bf16(b.x, b.y);
    r.w = cvt_pk_bf16(b.z, b.w);
    ((uint4*)out)[i] = r;
  }
}

// ---------------------------------------------------------------------------
// Persistent value GEMM, quarter-W: C_bf16[M,256] = A_bf16 @ W^T + bias.
// Grid = 1024 blocks (4 col-groups x 256 slots; 4 blocks/CU at 32 KB LDS ->
// 16 waves/CU, 2x the in-flight loads of the 64 KB version). W-quarter
// (64 cols x 256 K) staged once to XOR-swizzled LDS; persistent row-tile
// loop, zero barriers. XCD pairing: the 4 col-group blocks of one slot are
// bids s, s+256, s+512, s+768 (all == s mod 8) -> same XCD L2 serves A.
// ---------------------------------------------------------------------------
__global__ __launch_bounds__(256, 4) void gemm_val2_kernel(
    const unsigned short* __restrict__ A, const float* __restrict__ W,
    const float* __restrict__ bias, unsigned short* __restrict__ C, int M) {
  __shared__ short Ws[64 * 256];   // 32 KB, row stride 512 B, XOR-swizzled

  const int t  = threadIdx.x;
  const int w  = t >> 6;
  const int l  = t & 63;
  const int lr = l & 15;
  const int lc = l >> 4;
  const int col  = (int)(blockIdx.x >> 8);   // 0..3
  const int slot = (int)(blockIdx.x & 255);
  const int bn = col * 64;
  const int wm = (w >> 1) * 64;
  const int wn = (w & 1) * 32;

  // ---- stage W quarter (64 rows x 256 k), f32 -> bf16, swizzled, once ----
#pragma unroll 4
  for (int i = 0; i < 8; ++i) {
    const int idx = i * 256 + t;      // 2048 chunks of 8 floats
    const int row = idx >> 5;         // 32 chunks per row
    const int c16 = idx & 31;
    const float* wp = W + (size_t)(bn + row) * 256 + c16 * 8;
    const float4 w0 = *(const float4*)wp;
    const float4 w1 = *(const float4*)(wp + 4);
    uint4 p;
    p.x = cvt_pk_bf16(w0.x, w0.y);
    p.y = cvt_pk_bf16(w0.z, w0.w);
    p.z = cvt_pk_bf16(w1.x, w1.y);
    p.w = cvt_pk_bf16(w1.z, w1.w);
    const int boff = (row * 512 + c16 * 16) ^ ((row & 7) << 4);
    *(uint4*)((char*)Ws + boff) = p;
  }
  __syncthreads();

  float bv[2];
#pragma unroll
  for (int n = 0; n < 2; ++n) bv[n] = bias[bn + wn + n * 16 + lr];

  for (int tile = slot; tile * 128 < M; tile += 256) {
    const int bm = tile * 128;

    const unsigned short* apm[4];
#pragma unroll
    for (int m = 0; m < 4; ++m) {
      int row = bm + wm + m * 16 + lr;
      row = row < M ? row : M - 1;
      apm[m] = A + (size_t)row * 256 + lc * 8;
    }
    bf16x8 af[8][4];
#pragma unroll
    for (int kk = 0; kk < 8; ++kk)
#pragma unroll
      for (int m = 0; m < 4; ++m)
        af[kk][m] = *(const bf16x8*)(apm[m] + kk * 32);

    f32x4 acc[4][2];
#pragma unroll
    for (int m = 0; m < 4; ++m)
#pragma unroll
      for (int n = 0; n < 2; ++n) acc[m][n] = (f32x4){0.f, 0.f, 0.f, 0.f};

#pragma unroll
    for (int kk = 0; kk < 8; ++kk) {
      const int kb = kk * 64 + lc * 16;
      bf16x8 bfr[2];
#pragma unroll
      for (int n = 0; n < 2; ++n) {
        const int row = wn + n * 16 + lr;
        const int boff = (row * 512 + kb) ^ ((row & 7) << 4);
        bfr[n] = *(const bf16x8*)((const char*)Ws + boff);
      }
#pragma unroll
      for (int m = 0; m < 4; ++m)
#pragma unroll
        for (int n = 0; n < 2; ++n)
          acc[m][n] = __builtin_amdgcn_mfma_f32_16x16x32_bf16(af[kk][m], bfr[n], acc[m][n], 0, 0, 0);
    }

#pragma unroll
    for (int m = 0; m < 4; ++m) {
      const int rbase = bm + wm + m * 16 + lc * 4;
#pragma unroll
      for (int n = 0; n < 2; ++n) {
        const int cidx = bn + wn + n * 16 + lr;
#pragma unroll
        for (int j = 0; j < 4; ++j) {
          const int r = rbase + j;
          if (r < M) C[(size_t)r * 256 + cidx] = f2bf(acc[m][n][j] + bv[n]);
        }
      }
    }
  }
}

// ---------------------------------------------------------------------------
// Generic GEMM (f32 A): 128x128 tile, BK=64, reg-prefetch. Optional bf16 out.
// ---------------------------------------------------------------------------
__global__ __launch_bounds__(256) void gemm_mfma_kernel(
    const float* __restrict__ A, const float* __restrict__ W,
    const float* __restrict__ bias, void* __restrict__ Cv,
    int M, int N, int K, int relu, int out_bf16) {
  __shared__ short As[128 * 64];
  __shared__ short Bs[128 * 64];

  const int t  = threadIdx.x;
  const int bm = blockIdx.y * 128;
  const int bn = blockIdx.x * 128;
  const int w  = t >> 6;
  const int l  = t & 63;
  const int wm = (w >> 1) * 64;
  const int wn = (w & 1) * 64;

  f32x4 acc[4][4];
#pragma unroll
  for (int m = 0; m < 4; ++m)
#pragma unroll
    for (int n = 0; n < 4; ++n) acc[m][n] = (f32x4){0.f, 0.f, 0.f, 0.f};

  float4 pa[8], pw[8];
  auto load_tile = [&](int k0) {
#pragma unroll
    for (int i = 0; i < 8; ++i) {
      const int slot = i * 256 + t;
      const int row  = slot >> 4;
      const int c4   = slot & 15;
      const int ar   = bm + row;
      pa[i] = (ar < M) ? *(const float4*)(A + (size_t)ar * K + k0 + c4 * 4)
                       : make_float4(0.f, 0.f, 0.f, 0.f);
      pw[i] = *(const float4*)(W + (size_t)(bn + row) * K + k0 + c4 * 4);
    }
  };

  load_tile(0);

  for (int k0 = 0;;) {
#pragma unroll
    for (int i = 0; i < 8; ++i) {
      const int slot = i * 256 + t;
      const int row  = slot >> 4;
      const int c4   = slot & 15;
      const int boff = (row * 128 + c4 * 8) ^ ((row & 7) << 4);
      uint2 ap;
      ap.x = cvt_pk_bf16(pa[i].x, pa[i].y);
      ap.y = cvt_pk_bf16(pa[i].z, pa[i].w);
      *(uint2*)((char*)As + boff) = ap;
      uint2 wp;
      wp.x = cvt_pk_bf16(pw[i].x, pw[i].y);
      wp.y = cvt_pk_bf16(pw[i].z, pw[i].w);
      *(uint2*)((char*)Bs + boff) = wp;
    }
    __syncthreads();

    const int knext = k0 + 64;
    if (knext < K) load_tile(knext);

#pragma unroll
    for (int ks = 0; ks < 2; ++ks) {
      const int koff = (ks * 32 + (l >> 4) * 8) * 2;
      bf16x8 af[4], bfr[4];
#pragma unroll
      for (int m = 0; m < 4; ++m) {
        const int row = wm + m * 16 + (l & 15);
        af[m] = *(const bf16x8*)((const char*)As + ((row * 128 + koff) ^ ((row & 7) << 4)));
      }
#pragma unroll
      for (int n = 0; n < 4; ++n) {
        const int row = wn + n * 16 + (l & 15);
        bfr[n] = *(const bf16x8*)((const char*)Bs + ((row * 128 + koff) ^ ((row & 7) << 4)));
      }
#pragma unroll
      for (int m = 0; m < 4; ++m)
#pragma unroll
        for (int n = 0; n < 4; ++n)
          acc[m][n] = __builtin_amdgcn_mfma_f32_16x16x32_bf16(af[m], bfr[n], acc[m][n], 0, 0, 0);
    }

    k0 = knext;
    if (k0 >= K) break;
    __syncthreads();
  }

  const int lr4 = (l >> 4) * 4;
  const int lc  = l & 15;
#pragma unroll
  for (int m = 0; m < 4; ++m) {
    const int rbase = bm + wm + m * 16 + lr4;
#pragma unroll
    for (int n = 0; n < 4; ++n) {
      const int col = bn + wn + n * 16 + lc;
      const float bv = bias[col];
#pragma unroll
      for (int j = 0; j < 4; ++j) {
        const int r = rbase + j;
        if (r < M) {
          float v = acc[m][n][j] + bv;
          if (relu) v = fmaxf(v, 0.f);
          if (out_bf16)
            ((unsigned short*)Cv)[(size_t)r * N + col] = f2bf(v);
          else
            ((float*)Cv)[(size_t)r * N + col] = v;
        }
      }
    }
  }
}

// ---------------------------------------------------------------------------
// Generic GEMM, bf16 A: A staged as raw bf16 copies; W f32->bf16. f32 out.
// ---------------------------------------------------------------------------
__global__ __launch_bounds__(256) void gemm_mfma_bf16a_kernel(
    const unsigned short* __restrict__ A, const float* __restrict__ W,
    const float* __restrict__ bias, float* __restrict__ C,
    int M, int N, int K) {
  __shared__ short As[128 * 64];
  __shared__ short Bs[128 * 64];

  const int t  = threadIdx.x;
  const int bm = blockIdx.y * 128;
  const int bn = blockIdx.x * 128;
  const int w  = t >> 6;
  const int l  = t & 63;
  const int wm = (w >> 1) * 64;
  const int wn = (w & 1) * 64;

  f32x4 acc[4][4];
#pragma unroll
  for (int m = 0; m < 4; ++m)
#pragma unroll
    for (int n = 0; n < 4; ++n) acc[m][n] = (f32x4){0.f, 0.f, 0.f, 0.f};

  bf16x8 pa[4];
  float4 pw[8];
  auto load_tile = [&](int k0) {
#pragma unroll
    for (int i = 0; i < 4; ++i) {
      const int slot = i * 256 + t;        // 1024 chunks of 8 bf16
      const int row  = slot >> 3;
      const int c8   = slot & 7;
      int ar = bm + row;
      ar = ar < M ? ar : M - 1;
      pa[i] = *(const bf16x8*)(A + (size_t)ar * K + k0 + c8 * 8);
    }
#pragma unroll
    for (int i = 0; i < 8; ++i) {
      const int slot = i * 256 + t;
      const int row  = slot >> 4;
      const int c4   = slot & 15;
      pw[i] = *(const float4*)(W + (size_t)(bn + row) * K + k0 + c4 * 4);
    }
  };

  load_tile(0);

  for (int k0 = 0;;) {
#pragma unroll
    for (int i = 0; i < 4; ++i) {
      const int slot = i * 256 + t;
      const int row  = slot >> 3;
      const int c8   = slot & 7;
      const int boff = (row * 128 + c8 * 16) ^ ((row & 7) << 4);
      *(bf16x8*)((char*)As + boff) = pa[i];
    }
#pragma unroll
    for (int i = 0; i < 8; ++i) {
      const int slot = i * 256 + t;
      const int row  = slot >> 4;
      const int c4   = slot & 15;
      const int boff = (row * 128 + c4 * 8) ^ ((row & 7) << 4);
      uint2 wp;
      wp.x = cvt_pk_bf16(pw[i].x, pw[i].y);
      wp.y = cvt_pk_bf16(pw[i].z, pw[i].w);
      *(uint2*)((char*)Bs + boff) = wp;
    }
    __syncthreads();

    const int knext = k0 + 64;
    if (knext < K) load_tile(knext);

#pragma unroll
    for (int ks = 0; ks < 2; ++ks) {
      const int koff = (ks * 32 + (l >> 4) * 8) * 2;
      bf16x8 af[4], bfr[4];
#pragma unroll
      for (int m = 0; m < 4; ++m) {
        const int row = wm + m * 16 + (l & 15);
        af[m] = *(const bf16x8*)((const char*)As + ((row * 128 + koff) ^ ((row & 7) << 4)));
      }
#pragma unroll
      for (int n = 0; n < 4; ++n) {
        const int row = wn + n * 16 + (l & 15);
        bfr[n] = *(const bf16x8*)((const char*)Bs + ((row * 128 + koff) ^ ((row & 7) << 4)));
      }
#pragma unroll
      for (int m = 0; m < 4; ++m)
#pragma unroll
        for (int n = 0; n < 4; ++n)
          acc[m][n] = __builtin_amdgcn_mfma_f32_16x16x32_bf16(af[m], bfr[n], acc[m][n], 0, 0, 0);
    }

    k0 = knext;
    if (k0 >= K) break;
    __syncthreads();
  }

  const int lr4 = (l >> 4) * 4;
  const int lc  = l & 15;
#pragma unroll
  for (int m = 0; m < 4; ++m) {
    const int rbase = bm + wm + m * 16 + lr4;
#pragma unroll
    for (int n = 0; n < 4; ++n) {
      const int col = bn + wn + n * 16 + lc;
      const float bv = bias[col];
#pragma unroll
      for (int j = 0; j < 4; ++j) {
        const int r = rbase + j;
        if (r < M) C[(size_t)r * N + col] = acc[m][n][j] + bv;
      }
    }
  }
}

// ---------------------------------------------------------------------------
// Fused sampling-offset + attention-weight GEMM: logical N = 384, K = 256.
// ---------------------------------------------------------------------------
__global__ __launch_bounds__(256) void gemm_qoff_kernel(
    const float* __restrict__ A, const float* __restrict__ soW,
    const float* __restrict__ soB, const float* __restrict__ awW,
    const float* __restrict__ awB, float* __restrict__ offs,
    float* __restrict__ awr, int M) {
  __shared__ short As[128 * 64];
  __shared__ short Bs[128 * 64];

  const int t  = threadIdx.x;
  const int bm = blockIdx.y * 128;
  const int bn = blockIdx.x * 128;   // 0, 128, 256
  const int w  = t >> 6;
  const int l  = t & 63;
  const int wm = (w >> 1) * 64;
  const int wn = (w & 1) * 64;

  f32x4 acc[4][4];
#pragma unroll
  for (int m = 0; m < 4; ++m)
#pragma unroll
    for (int n = 0; n < 4; ++n) acc[m][n] = (f32x4){0.f, 0.f, 0.f, 0.f};

  float4 pa[8], pw[8];
  auto load_tile = [&](int k0) {
#pragma unroll
    for (int i = 0; i < 8; ++i) {
      const int slot = i * 256 + t;
      const int row  = slot >> 4;
      const int c4   = slot & 15;
      const int ar   = bm + row;
      pa[i] = (ar < M) ? *(const float4*)(A + (size_t)ar * 256 + k0 + c4 * 4)
                       : make_float4(0.f, 0.f, 0.f, 0.f);
      const int gn = bn + row;
      const float* Wp = (gn < 256) ? (soW + (size_t)gn * 256)
                                   : (awW + (size_t)(gn - 256) * 256);
      pw[i] = *(const float4*)(Wp + k0 + c4 * 4);
    }
  };

  load_tile(0);

  for (int k0 = 0;;) {
#pragma unroll
    for (int i = 0; i < 8; ++i) {
      const int slot = i * 256 + t;
      const int row  = slot >> 4;
      const int c4   = slot & 15;
      const int boff = (row * 128 + c4 * 8) ^ ((row & 7) << 4);
      uint2 ap;
      ap.x = cvt_pk_bf16(pa[i].x, pa[i].y);
      ap.y = cvt_pk_bf16(pa[i].z, pa[i].w);
      *(uint2*)((char*)As + boff) = ap;
      uint2 wp;
      wp.x = cvt_pk_bf16(pw[i].x, pw[i].y);
      wp.y = cvt_pk_bf16(pw[i].z, pw[i].w);
      *(uint2*)((char*)Bs + boff) = wp;
    }
    __syncthreads();

    const int knext = k0 + 64;
    if (knext < 256) load_tile(knext);

#pragma unroll
    for (int ks = 0; ks < 2; ++ks) {
      const int koff = (ks * 32 + (l >> 4) * 8) * 2;
      bf16x8 af[4], bfr[4];
#pragma unroll
      for (int m = 0; m < 4; ++m) {
        const int row = wm + m * 16 + (l & 15);
        af[m] = *(const bf16x8*)((const char*)As + ((row * 128 + koff) ^ ((row & 7) << 4)));
      }
#pragma unroll
      for (int n = 0; n < 4; ++n) {
        const int row = wn + n * 16 + (l & 15);
        bfr[n] = *(const bf16x8*)((const char*)Bs + ((row * 128 + koff) ^ ((row & 7) << 4)));
      }
#pragma unroll
      for (int m = 0; m < 4; ++m)
#pragma unroll
        for (int n = 0; n < 4; ++n)
          acc[m][n] = __builtin_amdgcn_mfma_f32_16x16x32_bf16(af[m], bfr[n], acc[m][n], 0, 0, 0);
    }

    k0 = knext;
    if (k0 >= 256) break;
    __syncthreads();
  }

  const int lr4 = (l >> 4) * 4;
  const int lc  = l & 15;
#pragma unroll
  for (int m = 0; m < 4; ++m) {
    const int rbase = bm + wm + m * 16 + lr4;
#pragma unroll
    for (int n = 0; n < 4; ++n) {
      const int col = bn + wn + n * 16 + lc;
      const float bv = (col < 256) ? soB[col] : awB[col - 256];
#pragma unroll
      for (int j = 0; j < 4; ++j) {
        const int r = rbase + j;
        if (r < M) {
          const float v = acc[m][n][j] + bv;
          if (col < 256) offs[(size_t)r * 256 + col] = v;
          else           awr[(size_t)r * 128 + col - 256] = v;
        }
      }
    }
  }
}

// ---------------------------------------------------------------------------
// bf16 MFMA flash self-attention, swapped-QK^T + max-free softmax. bf16 out.
// ---------------------------------------------------------------------------
__global__ __launch_bounds__(256) void self_attn_mfma_kernel(
    const unsigned short* __restrict__ qkv, unsigned short* __restrict__ out) {
  const int b = blockIdx.y >> 3;
  const int h = blockIdx.y & 7;
  const int t = threadIdx.x;
  const int w = t >> 6;
  const int l = t & 63;
  const int lr = l & 15;
  const int lc = l >> 4;

  __shared__ short Klds[64 * 40];
  __shared__ short Vt[32 * 68];
  __shared__ short Plds[4][2 * 16 * 68];

  const float scale = 0.17677669529663687f;
  const int qb0 = blockIdx.x * 128 + w * 16;

  bf16x8 qf[2] = {};
#pragma unroll
  for (int qt = 0; qt < 2; ++qt) {
    const int qr = qb0 + qt * 64 + lr;
    if (qr < kNQ)
      qf[qt] = *(const bf16x8*)(qkv + ((size_t)(b * kNQ + qr)) * 768 + h * 32 + lc * 8);
  }

  f32x4 o[2][2];
#pragma unroll
  for (int qt = 0; qt < 2; ++qt)
#pragma unroll
    for (int dh = 0; dh < 2; ++dh) o[qt][dh] = (f32x4){0.f, 0.f, 0.f, 0.f};
  const f32x4 zero4 = {0.f, 0.f, 0.f, 0.f};
  float lsum[2] = {0.f, 0.f};

  const int skey = t & 63, sc = t >> 6;
  bf16x8 kreg = {}, vreg = {};
  auto load_kv = [&](int tb) {
    const int kr = tb + skey;
    if (kr < kNQ) {
      const unsigned short* p = qkv + ((size_t)(b * kNQ + kr)) * 768 + h * 32 + sc * 8;
      kreg = *(const bf16x8*)(p + 256);
      vreg = *(const bf16x8*)(p + 512);
    } else {
      kreg = (bf16x8){}; vreg = (bf16x8){};
    }
  };

  load_kv(0);

  for (int tb = 0; tb < kNQ; tb += 64) {
    *(bf16x8*)&Klds[skey * 40 + sc * 8] = kreg;
#pragma unroll
    for (int i = 0; i < 8; ++i) Vt[(sc * 8 + i) * 68 + skey] = vreg[i];
    __syncthreads();

    if (tb + 64 < kNQ) load_kv(tb + 64);

    f32x4 s[2][4];
#pragma unroll
    for (int kt = 0; kt < 4; ++kt) {
      bf16x8 kf = *(const bf16x8*)&Klds[(kt * 16 + lr) * 40 + lc * 8];
      s[0][kt] = __builtin_amdgcn_mfma_f32_16x16x32_bf16(kf, qf[0], zero4, 0, 0, 0);
      s[1][kt] = __builtin_amdgcn_mfma_f32_16x16x32_bf16(kf, qf[1], zero4, 0, 0, 0);
    }

#pragma unroll
    for (int qt = 0; qt < 2; ++qt) {
      short* Pw = Plds[w] + qt * (16 * 68);
      float ls = 0.f;
#pragma unroll
      for (int kt = 0; kt < 4; ++kt) {
        float p[4];
#pragma unroll
        for (int j = 0; j < 4; ++j) {
          const int kg = tb + kt * 16 + lc * 4 + j;
          const float e = __expf(s[qt][kt][j] * scale);
          p[j] = (kg < kNQ) ? e : 0.f;
          ls += p[j];
        }
        uint2 pk;
        pk.x = cvt_pk_bf16(p[0], p[1]);
        pk.y = cvt_pk_bf16(p[2], p[3]);
        *(uint2*)&Pw[lr * 68 + kt * 16 + lc * 4] = pk;
      }
      lsum[qt] += ls;
    }

    bf16x8 v00 = *(const bf16x8*)&Vt[lr * 68 + lc * 8];
    bf16x8 v01 = *(const bf16x8*)&Vt[lr * 68 + 32 + lc * 8];
    bf16x8 v10 = *(const bf16x8*)&Vt[(16 + lr) * 68 + lc * 8];
    bf16x8 v11 = *(const bf16x8*)&Vt[(16 + lr) * 68 + 32 + lc * 8];
#pragma unroll
    for (int qt = 0; qt < 2; ++qt) {
      const short* Pw = Plds[w] + qt * (16 * 68);
      bf16x8 pa0 = *(const bf16x8*)&Pw[lr * 68 + lc * 8];
      bf16x8 pa1 = *(const bf16x8*)&Pw[lr * 68 + 32 + lc * 8];
      o[qt][0] = __builtin_amdgcn_mfma_f32_16x16x32_bf16(pa0, v00, o[qt][0], 0, 0, 0);
      o[qt][0] = __builtin_amdgcn_mfma_f32_16x16x32_bf16(pa1, v01, o[qt][0], 0, 0, 0);
      o[qt][1] = __builtin_amdgcn_mfma_f32_16x16x32_bf16(pa0, v10, o[qt][1], 0, 0, 0);
      o[qt][1] = __builtin_amdgcn_mfma_f32_16x16x32_bf16(pa1, v11, o[qt][1], 0, 0, 0);
    }
    __syncthreads();
  }

#pragma unroll
  for (int qt = 0; qt < 2; ++qt) {
    float lt = lsum[qt];
    lt += __shfl_xor(lt, 16);
    lt += __shfl_xor(lt, 32);
#pragma unroll
    for (int j = 0; j < 4; ++j) {
      const float lq = __shfl(lt, lc * 4 + j);
      const int q = qb0 + qt * 64 + lc * 4 + j;
      if (q < kNQ) {
        const float inv = 1.f / lq;
        unsigned short* op = out + ((size_t)(b * kNQ + q)) * 256 + h * 32;
        op[lr]      = f2bf(o[qt][0][j] * inv);
        op[16 + lr] = f2bf(o[qt][1][j] * inv);
      }
    }
  }
}

// ---------------------------------------------------------------------------
// out = LayerNorm(x + res) * g + b over rows of 256. One block per row.
// ---------------------------------------------------------------------------
__global__ __launch_bounds__(256) void ln_res_kernel(
    const float* __restrict__ x, const float* __restrict__ res,
    const float* __restrict__ g, const float* __restrict__ bta,
    float* __restrict__ out) {
  const int row = blockIdx.x;
  const int t = threadIdx.x;
  const size_t idx = (size_t)row * 256 + t;
  const float v = x[idx] + res[idx];
  float s = v, s2 = v * v;
#pragma unroll
  for (int mask = 1; mask < 64; mask <<= 1) {
    s  += __shfl_xor(s, mask);
    s2 += __shfl_xor(s2, mask);
  }
  __shared__ float ws[4], ws2[4];
  if ((t & 63) == 0) { ws[t >> 6] = s; ws2[t >> 6] = s2; }
  __syncthreads();
  const float S  = ws[0] + ws[1] + ws[2] + ws[3];
  const float S2 = ws2[0] + ws2[1] + ws2[2] + ws2[3];
  const float mean = S * (1.f / 256.f);
  const float var  = S2 * (1.f / 256.f) - mean * mean;
  const float rstd = rsqrtf(var + 1e-5f);
  out[idx] = (v - mean) * rstd * g[t] + bta[t];
}

// ---------------------------------------------------------------------------
// MS deformable attention, 16B gathers. One block per (b,q).
// Thread t: channel octet oct = t&31 (ch = oct*8, head h = oct>>2),
// sample-group sg = t>>5 handles samples sg*2, sg*2+1 of its head.
// 8 uint4 gathers / thread (vs 16 uint2); partials in part[8][256].
// ---------------------------------------------------------------------------
__global__ __launch_bounds__(256) void deform_kernel(
    const unsigned short* __restrict__ value,   // (B, LV, 256) bf16
    const float* __restrict__ offs,    // (B*NQ, 256)
    const float* __restrict__ awr,     // (B*NQ, 128)
    const float* __restrict__ refp,    // (B, NQ, 4, 2)
    unsigned short* __restrict__ out) {  // (B*NQ, 256) bf16
  const int bq = blockIdx.x;
  const int b = bq / kNQ;
  const int t = threadIdx.x;

  __shared__ int2  cpk[128][4];   // (idx, weight-bits) at pos = lp*8 + h
  __shared__ float part[8][256];  // per-sample-group channel partials

  if (t < 128) {
    const float a = awr[(size_t)bq * 128 + t];
    float mx = a;
#pragma unroll
    for (int mask = 1; mask < 16; mask <<= 1) mx = fmaxf(mx, __shfl_xor(mx, mask));
    const float e = __expf(a - mx);
    float se = e;
#pragma unroll
    for (int mask = 1; mask < 16; mask <<= 1) se += __shfl_xor(se, mask);
    const float aw = e / se;

    const int h = t >> 4, lp = t & 15, lvl = lp >> 2;
    const int HL[4] = {100, 50, 25, 13};
    const int WL[4] = {100, 50, 25, 13};
    const int ST[4] = {0, 10000, 12500, 13125};
    const int Hl = HL[lvl], Wl = WL[lvl], st = ST[lvl];
    const float rx = refp[((size_t)bq * 4 + lvl) * 2 + 0];
    const float ry = refp[((size_t)bq * 4 + lvl) * 2 + 1];
    const float ox = offs[(size_t)bq * 256 + h * 32 + lp * 2 + 0];
    const float oy = offs[(size_t)bq * 256 + h * 32 + lp * 2 + 1];
    const float x = rx * (float)Wl + ox - 0.5f;
    const float y = ry * (float)Hl + oy - 0.5f;
    const float x0f = floorf(x), y0f = floorf(y);
    const int x0 = (int)x0f, y0 = (int)y0f;
    const float lx = x - x0f, ly = y - y0f;
    const float wts[4] = {(1.f - lx) * (1.f - ly), lx * (1.f - ly),
                          (1.f - lx) * ly,         lx * ly};
    const int ys[4] = {y0, y0, y0 + 1, y0 + 1};
    const int xs[4] = {x0, x0 + 1, x0, x0 + 1};
    const int pos = lp * 8 + h;
#pragma unroll
    for (int c = 0; c < 4; ++c) {
      const int yy = ys[c], xx = xs[c];
      const bool valid = (yy >= 0) && (yy < Hl) && (xx >= 0) && (xx < Wl);
      const int yc = min(max(yy, 0), Hl - 1);
      const int xc = min(max(xx, 0), Wl - 1);
      const float wf = valid ? wts[c] * aw : 0.f;
      cpk[pos][c] = make_int2(st + yc * Wl + xc, __float_as_int(wf));
    }
  }
  __syncthreads();

  const int sg  = t >> 5;        // sample group: samples sg*2, sg*2+1
  const int oct = t & 31;        // channel octet
  const int h   = oct >> 2;      // head (4 octets / head)
  const int ch  = oct * 8;
  const unsigned short* vb = value + (size_t)b * kLV * 256 + ch;

  float a0 = 0.f, a1 = 0.f, a2 = 0.f, a3 = 0.f;
  float a4 = 0.f, a5 = 0.f, a6 = 0.f, a7 = 0.f;
#pragma unroll
  for (int si = 0; si < 2; ++si) {
    const int lp = sg * 2 + si;
#pragma unroll
    for (int c = 0; c < 4; ++c) {
      const int2 p = cpk[lp * 8 + h][c];
      const float wt = __int_as_float(p.y);
      const uint4 v = *(const uint4*)(vb + (size_t)p.x * 256);
      a0 = fmaf(wt, bf2f((unsigned short)(v.x & 0xffff)), a0);
      a1 = fmaf(wt, bf2f((unsigned short)(v.x >> 16)), a1);
      a2 = fmaf(wt, bf2f((unsigned short)(v.y & 0xffff)), a2);
      a3 = fmaf(wt, bf2f((unsigned short)(v.y >> 16)), a3);
      a4 = fmaf(wt, bf2f((unsigned short)(v.z & 0xffff)), a4);
      a5 = fmaf(wt, bf2f((unsigned short)(v.z >> 16)), a5);
      a6 = fmaf(wt, bf2f((unsigned short)(v.w & 0xffff)), a6);
      a7 = fmaf(wt, bf2f((unsigned short)(v.w >> 16)), a7);
    }
  }
  *(float4*)&part[sg][ch]     = make_float4(a0, a1, a2, a3);
  *(float4*)&part[sg][ch + 4] = make_float4(a4, a5, a6, a7);
  __syncthreads();

  float r = 0.f;
#pragma unroll
  for (int s2 = 0; s2 < 8; ++s2) r += part[s2][t];
  out[(size_t)bq * 256 + t] = f2bf(r);
}

}  // namespace

extern "C" void kernel_launch(void* const* d_in, const int* in_sizes, int n_in,
                              void* d_out, int out_size, void* d_ws, size_t ws_size,
                              hipStream_t stream) {
  const float* query  = (const float*)d_in[0];
  const float* refp   = (const float*)d_in[1];
  const float* memory = (const float*)d_in[2];
  const float* in_w  = (const float*)d_in[6];
  const float* in_b  = (const float*)d_in[7];
  const float* out_w = (const float*)d_in[8];
  const float* out_b = (const float*)d_in[9];
  const float* ln1g  = (const float*)d_in[10];
  const float* ln1b  = (const float*)d_in[11];
  const float* vp_w  = (const float*)d_in[12];
  const float* vp_b  = (const float*)d_in[13];
  const float* so_w  = (const float*)d_in[14];
  const float* so_b  = (const float*)d_in[15];
  const float* aw_w  = (const float*)d_in[16];
  const float* aw_b  = (const float*)d_in[17];
  const float* ca_w  = (const float*)d_in[18];
  const float* ca_b  = (const float*)d_in[19];
  const float* ln2g  = (const float*)d_in[20];
  const float* ln2b  = (const float*)d_in[21];
  const float* f1_w  = (const float*)d_in[22];
  const float* f1_b  = (const float*)d_in[23];
  const float* f2_w  = (const float*)d_in[24];
  const float* f2_b  = (const float*)d_in[25];
  const float* ln3g  = (const float*)d_in[26];
  const float* ln3b  = (const float*)d_in[27];
  float* out = (float*)d_out;

  const int MQ = kB * kNQ;   // 7200
  const int MV = kB * kLV;   // 106352

  float* ws = (float*)d_ws;
  size_t o = 0;
  float* qkvr = ws;                             // region: qkv bf16 / ffh bf16
  o += (size_t)MQ * kDFF;
  float* sar  = ws + o;  o += (size_t)MQ * kD;  // sa bf16
  float* q1   = ws + o;  o += (size_t)MQ * kD;
  float* valr = ws + o;  o += (size_t)MV * kD;  // region: val_bf | m_bf (both bf16)
  float* offs = ws + o;  o += (size_t)MQ * kD;
  float* awr  = ws + o;  o += (size_t)MQ * 128;
  float* dfor = ws + o;  o += (size_t)MQ * kD;  // dfo bf16
  float* q2   = ws + o;  o += (size_t)MQ * kD;
  float* tmp  = ws + o;  o += (size_t)MQ * kD;
  (void)ws_size; (void)in_sizes; (void)n_in; (void)out_size;

  unsigned short* qkv_bf = (unsigned short*)qkvr;                         // MQ*768 bf16
  unsigned short* ffh_bf = (unsigned short*)qkvr;                         // MQ*1024 bf16 (qkv dead by then)
  unsigned short* sa_bf  = (unsigned short*)sar;                          // MQ*256 bf16
  unsigned short* dfo_bf = (unsigned short*)dfor;                         // MQ*256 bf16
  unsigned short* val_bf = (unsigned short*)valr;                         // MV*256 bf16
  unsigned short* m_bf   = (unsigned short*)(valr + (size_t)MV * kD / 2); // MV*256 bf16

  const dim3 blk(256);
  auto g128 = [](int M, int N) { return dim3((unsigned)((N + 127) / 128), (unsigned)((M + 127) / 128)); };

  // 0. memory -> bf16 (streaming)
  f32_to_bf16_kernel<<<2048, blk, 0, stream>>>(memory, (unsigned*)m_bf, MV * kD / 8);
  // 1. qkv = query @ in_proj^T + b  (bf16 out)
  gemm_mfma_kernel<<<g128(MQ, 768), blk, 0, stream>>>(query, in_w, in_b, qkv_bf, MQ, 768, kD, 0, 1);
  // 2. self-attention -> sa (bf16 out)
  self_attn_mfma_kernel<<<dim3((kNQ + 127) / 128, kB * 8), blk, 0, stream>>>(qkv_bf, sa_bf);
  // 3. out-proj (bf16 A) -> tmp
  gemm_mfma_bf16a_kernel<<<g128(MQ, kD), blk, 0, stream>>>(sa_bf, out_w, out_b, tmp, MQ, kD, kD);
  // 4. q1 = LN(query + tmp)
  ln_res_kernel<<<MQ, blk, 0, stream>>>(query, tmp, ln1g, ln1b, q1);
  // 5. value = m_bf @ value_proj^T + b  (persistent quarter-W, 4 blocks/CU)
  gemm_val2_kernel<<<1024, blk, 0, stream>>>(m_bf, vp_w, vp_b, val_bf, MV);
  // 6+7. fused sampling offsets + attention weights
  gemm_qoff_kernel<<<dim3(3, (MQ + 127) / 128), blk, 0, stream>>>(
      q1, so_w, so_b, aw_w, aw_b, offs, awr, MQ);
  // 8. deformable attention -> dfo (bf16 out, 16B gathers)
  deform_kernel<<<MQ, blk, 0, stream>>>(val_bf, offs, awr, refp, dfo_bf);
  // 9. ca out-proj (bf16 A) -> tmp
  gemm_mfma_bf16a_kernel<<<g128(MQ, kD), blk, 0, stream>>>(dfo_bf, ca_w, ca_b, tmp, MQ, kD, kD);
  // 10. q2 = LN(q1 + tmp)
  ln_res_kernel<<<MQ, blk, 0, stream>>>(q1, tmp, ln2g, ln2b, q2);
  // 11. ffh = relu(q2 @ ffn_w1^T + b1)  (bf16 out)
  gemm_mfma_kernel<<<g128(MQ, kDFF), blk, 0, stream>>>(q2, f1_w, f1_b, ffh_bf, MQ, kDFF, kD, 1, 1);
  // 12. ffn2 (bf16 A, K=1024) -> tmp
  gemm_mfma_bf16a_kernel<<<g128(MQ, kD), blk, 0, stream>>>(ffh_bf, f2_w, f2_b, tmp, MQ, kD, kDFF);
  // 13. out = LN(q2 + tmp)
  ln_res_kernel<<<MQ, blk, 0, stream>>>(q2, tmp, ln3g, ln3b, out);
}

// Round 17
// 271.419 us; speedup vs baseline: 1.0962x; 1.0962x over previous
//
#include <hip/hip_runtime.h>
#include <cstddef>

namespace {

constexpr int kB   = 8;
constexpr int kNQ  = 900;
constexpr int kD   = 256;
constexpr int kDFF = 1024;
constexpr int kLV  = 13294;

typedef short bf16x8 __attribute__((ext_vector_type(8)));
typedef float f32x4  __attribute__((ext_vector_type(4)));

__device__ inline unsigned short f2bf(float f) {
  union { float f; unsigned u; } v; v.f = f;
  return (unsigned short)((v.u + 0x7FFF + ((v.u >> 16) & 1)) >> 16);
}

__device__ inline float bf2f(unsigned short u) {
  union { unsigned u; float f; } v; v.u = (unsigned)u << 16;
  return v.f;
}

// HW packed f32->bf16 (RNE)
__device__ inline unsigned cvt_pk_bf16(float a, float b) {
  unsigned r;
  asm("v_cvt_pk_bf16_f32 %0, %1, %2" : "=v"(r) : "v"(a), "v"(b));
  return r;
}

// ---------------------------------------------------------------------------
// Streaming f32 -> bf16 convert (8 floats / thread / iter).
// ---------------------------------------------------------------------------
__global__ __launch_bounds__(256) void f32_to_bf16_kernel(
    const float* __restrict__ in, unsigned* __restrict__ out, int n8) {
  int i = blockIdx.x * 256 + threadIdx.x;
  const int stride = gridDim.x * 256;
  for (; i < n8; i += stride) {
    const float4 a = ((const float4*)in)[(size_t)i * 2];
    const float4 b = ((const float4*)in)[(size_t)i * 2 + 1];
    uint4 r;
    r.x = cvt_pk_bf16(a.x, a.y);
    r.y = cvt_pk_bf16(a.z, a.w);
    r.z = cvt_pk_bf16(b.x, b.y);
    r.w = cvt_pk_bf16(b.z, b.w);
    ((uint4*)out)[i] = r;
  }
}

// ---------------------------------------------------------------------------
// Persistent value GEMM: C_bf16[M,256] = A_bf16[M,256] @ W_f32[256,256]^T + b.
// Grid = 512 blocks (2/CU). W-half staged once to swizzled LDS; persistent
// row-tile loop with zero barriers; XCD col-pairing for A L2 reuse.
// (r13/r15 proven structure; quarter-W (r16) and fused-cvt (r12) both regress.)
// ---------------------------------------------------------------------------
__global__ __launch_bounds__(256, 2) void gemm_val2_kernel(
    const unsigned short* __restrict__ A, const float* __restrict__ W,
    const float* __restrict__ bias, unsigned short* __restrict__ C, int M) {
  __shared__ short Ws[128 * 256];   // 64 KB, row stride 512 B, XOR-swizzled

  const int t  = threadIdx.x;
  const int w  = t >> 6;
  const int l  = t & 63;
  const int lr = l & 15;
  const int lc = l >> 4;
  const int col  = (int)(blockIdx.x >> 8);   // 0 or 1
  const int slot = (int)(blockIdx.x & 255);
  const int bn = col * 128;
  const int wm = (w >> 1) * 64;
  const int wn = (w & 1) * 64;

#pragma unroll 4
  for (int i = 0; i < 16; ++i) {
    const int idx = i * 256 + t;
    const int row = idx >> 5;
    const int c16 = idx & 31;
    const float* wp = W + (size_t)(bn + row) * 256 + c16 * 8;
    const float4 w0 = *(const float4*)wp;
    const float4 w1 = *(const float4*)(wp + 4);
    uint4 p;
    p.x = cvt_pk_bf16(w0.x, w0.y);
    p.y = cvt_pk_bf16(w0.z, w0.w);
    p.z = cvt_pk_bf16(w1.x, w1.y);
    p.w = cvt_pk_bf16(w1.z, w1.w);
    const int boff = (row * 512 + c16 * 16) ^ ((row & 7) << 4);
    *(uint4*)((char*)Ws + boff) = p;
  }
  __syncthreads();

  float bv[4];
#pragma unroll
  for (int n = 0; n < 4; ++n) bv[n] = bias[bn + wn + n * 16 + lr];

  for (int tile = slot; tile * 128 < M; tile += 256) {
    const int bm = tile * 128;

    const unsigned short* apm[4];
#pragma unroll
    for (int m = 0; m < 4; ++m) {
      int row = bm + wm + m * 16 + lr;
      row = row < M ? row : M - 1;
      apm[m] = A + (size_t)row * 256 + lc * 8;
    }
    bf16x8 af[8][4];
#pragma unroll
    for (int kk = 0; kk < 8; ++kk)
#pragma unroll
      for (int m = 0; m < 4; ++m)
        af[kk][m] = *(const bf16x8*)(apm[m] + kk * 32);

    f32x4 acc[4][4];
#pragma unroll
    for (int m = 0; m < 4; ++m)
#pragma unroll
      for (int n = 0; n < 4; ++n) acc[m][n] = (f32x4){0.f, 0.f, 0.f, 0.f};

#pragma unroll
    for (int kk = 0; kk < 8; ++kk) {
      const int kb = kk * 64 + lc * 16;
      bf16x8 bfr[4];
#pragma unroll
      for (int n = 0; n < 4; ++n) {
        const int row = wn + n * 16 + lr;
        const int boff = (row * 512 + kb) ^ ((row & 7) << 4);
        bfr[n] = *(const bf16x8*)((const char*)Ws + boff);
      }
#pragma unroll
      for (int m = 0; m < 4; ++m)
#pragma unroll
        for (int n = 0; n < 4; ++n)
          acc[m][n] = __builtin_amdgcn_mfma_f32_16x16x32_bf16(af[kk][m], bfr[n], acc[m][n], 0, 0, 0);
    }

#pragma unroll
    for (int m = 0; m < 4; ++m) {
      const int rbase = bm + wm + m * 16 + lc * 4;
#pragma unroll
      for (int n = 0; n < 4; ++n) {
        const int cidx = bn + wn + n * 16 + lr;
#pragma unroll
        for (int j = 0; j < 4; ++j) {
          const int r = rbase + j;
          if (r < M) C[(size_t)r * 256 + cidx] = f2bf(acc[m][n][j] + bv[n]);
        }
      }
    }
  }
}

// ---------------------------------------------------------------------------
// Generic GEMM (f32 A): 128x128 tile, BK=64, reg-prefetch. Optional bf16 out.
// ---------------------------------------------------------------------------
__global__ __launch_bounds__(256) void gemm_mfma_kernel(
    const float* __restrict__ A, const float* __restrict__ W,
    const float* __restrict__ bias, void* __restrict__ Cv,
    int M, int N, int K, int relu, int out_bf16) {
  __shared__ short As[128 * 64];
  __shared__ short Bs[128 * 64];

  const int t  = threadIdx.x;
  const int bm = blockIdx.y * 128;
  const int bn = blockIdx.x * 128;
  const int w  = t >> 6;
  const int l  = t & 63;
  const int wm = (w >> 1) * 64;
  const int wn = (w & 1) * 64;

  f32x4 acc[4][4];
#pragma unroll
  for (int m = 0; m < 4; ++m)
#pragma unroll
    for (int n = 0; n < 4; ++n) acc[m][n] = (f32x4){0.f, 0.f, 0.f, 0.f};

  float4 pa[8], pw[8];
  auto load_tile = [&](int k0) {
#pragma unroll
    for (int i = 0; i < 8; ++i) {
      const int slot = i * 256 + t;
      const int row  = slot >> 4;
      const int c4   = slot & 15;
      const int ar   = bm + row;
      pa[i] = (ar < M) ? *(const float4*)(A + (size_t)ar * K + k0 + c4 * 4)
                       : make_float4(0.f, 0.f, 0.f, 0.f);
      pw[i] = *(const float4*)(W + (size_t)(bn + row) * K + k0 + c4 * 4);
    }
  };

  load_tile(0);

  for (int k0 = 0;;) {
#pragma unroll
    for (int i = 0; i < 8; ++i) {
      const int slot = i * 256 + t;
      const int row  = slot >> 4;
      const int c4   = slot & 15;
      const int boff = (row * 128 + c4 * 8) ^ ((row & 7) << 4);
      uint2 ap;
      ap.x = cvt_pk_bf16(pa[i].x, pa[i].y);
      ap.y = cvt_pk_bf16(pa[i].z, pa[i].w);
      *(uint2*)((char*)As + boff) = ap;
      uint2 wp;
      wp.x = cvt_pk_bf16(pw[i].x, pw[i].y);
      wp.y = cvt_pk_bf16(pw[i].z, pw[i].w);
      *(uint2*)((char*)Bs + boff) = wp;
    }
    __syncthreads();

    const int knext = k0 + 64;
    if (knext < K) load_tile(knext);

#pragma unroll
    for (int ks = 0; ks < 2; ++ks) {
      const int koff = (ks * 32 + (l >> 4) * 8) * 2;
      bf16x8 af[4], bfr[4];
#pragma unroll
      for (int m = 0; m < 4; ++m) {
        const int row = wm + m * 16 + (l & 15);
        af[m] = *(const bf16x8*)((const char*)As + ((row * 128 + koff) ^ ((row & 7) << 4)));
      }
#pragma unroll
      for (int n = 0; n < 4; ++n) {
        const int row = wn + n * 16 + (l & 15);
        bfr[n] = *(const bf16x8*)((const char*)Bs + ((row * 128 + koff) ^ ((row & 7) << 4)));
      }
#pragma unroll
      for (int m = 0; m < 4; ++m)
#pragma unroll
        for (int n = 0; n < 4; ++n)
          acc[m][n] = __builtin_amdgcn_mfma_f32_16x16x32_bf16(af[m], bfr[n], acc[m][n], 0, 0, 0);
    }

    k0 = knext;
    if (k0 >= K) break;
    __syncthreads();
  }

  const int lr4 = (l >> 4) * 4;
  const int lc  = l & 15;
#pragma unroll
  for (int m = 0; m < 4; ++m) {
    const int rbase = bm + wm + m * 16 + lr4;
#pragma unroll
    for (int n = 0; n < 4; ++n) {
      const int col = bn + wn + n * 16 + lc;
      const float bv = bias[col];
#pragma unroll
      for (int j = 0; j < 4; ++j) {
        const int r = rbase + j;
        if (r < M) {
          float v = acc[m][n][j] + bv;
          if (relu) v = fmaxf(v, 0.f);
          if (out_bf16)
            ((unsigned short*)Cv)[(size_t)r * N + col] = f2bf(v);
          else
            ((float*)Cv)[(size_t)r * N + col] = v;
        }
      }
    }
  }
}

// ---------------------------------------------------------------------------
// Generic GEMM, bf16 A: A staged as raw bf16 copies; W f32->bf16. f32 out.
// ---------------------------------------------------------------------------
__global__ __launch_bounds__(256) void gemm_mfma_bf16a_kernel(
    const unsigned short* __restrict__ A, const float* __restrict__ W,
    const float* __restrict__ bias, float* __restrict__ C,
    int M, int N, int K) {
  __shared__ short As[128 * 64];
  __shared__ short Bs[128 * 64];

  const int t  = threadIdx.x;
  const int bm = blockIdx.y * 128;
  const int bn = blockIdx.x * 128;
  const int w  = t >> 6;
  const int l  = t & 63;
  const int wm = (w >> 1) * 64;
  const int wn = (w & 1) * 64;

  f32x4 acc[4][4];
#pragma unroll
  for (int m = 0; m < 4; ++m)
#pragma unroll
    for (int n = 0; n < 4; ++n) acc[m][n] = (f32x4){0.f, 0.f, 0.f, 0.f};

  bf16x8 pa[4];
  float4 pw[8];
  auto load_tile = [&](int k0) {
#pragma unroll
    for (int i = 0; i < 4; ++i) {
      const int slot = i * 256 + t;        // 1024 chunks of 8 bf16
      const int row  = slot >> 3;
      const int c8   = slot & 7;
      int ar = bm + row;
      ar = ar < M ? ar : M - 1;
      pa[i] = *(const bf16x8*)(A + (size_t)ar * K + k0 + c8 * 8);
    }
#pragma unroll
    for (int i = 0; i < 8; ++i) {
      const int slot = i * 256 + t;
      const int row  = slot >> 4;
      const int c4   = slot & 15;
      pw[i] = *(const float4*)(W + (size_t)(bn + row) * K + k0 + c4 * 4);
    }
  };

  load_tile(0);

  for (int k0 = 0;;) {
#pragma unroll
    for (int i = 0; i < 4; ++i) {
      const int slot = i * 256 + t;
      const int row  = slot >> 3;
      const int c8   = slot & 7;
      const int boff = (row * 128 + c8 * 16) ^ ((row & 7) << 4);
      *(bf16x8*)((char*)As + boff) = pa[i];
    }
#pragma unroll
    for (int i = 0; i < 8; ++i) {
      const int slot = i * 256 + t;
      const int row  = slot >> 4;
      const int c4   = slot & 15;
      const int boff = (row * 128 + c4 * 8) ^ ((row & 7) << 4);
      uint2 wp;
      wp.x = cvt_pk_bf16(pw[i].x, pw[i].y);
      wp.y = cvt_pk_bf16(pw[i].z, pw[i].w);
      *(uint2*)((char*)Bs + boff) = wp;
    }
    __syncthreads();

    const int knext = k0 + 64;
    if (knext < K) load_tile(knext);

#pragma unroll
    for (int ks = 0; ks < 2; ++ks) {
      const int koff = (ks * 32 + (l >> 4) * 8) * 2;
      bf16x8 af[4], bfr[4];
#pragma unroll
      for (int m = 0; m < 4; ++m) {
        const int row = wm + m * 16 + (l & 15);
        af[m] = *(const bf16x8*)((const char*)As + ((row * 128 + koff) ^ ((row & 7) << 4)));
      }
#pragma unroll
      for (int n = 0; n < 4; ++n) {
        const int row = wn + n * 16 + (l & 15);
        bfr[n] = *(const bf16x8*)((const char*)Bs + ((row * 128 + koff) ^ ((row & 7) << 4)));
      }
#pragma unroll
      for (int m = 0; m < 4; ++m)
#pragma unroll
        for (int n = 0; n < 4; ++n)
          acc[m][n] = __builtin_amdgcn_mfma_f32_16x16x32_bf16(af[m], bfr[n], acc[m][n], 0, 0, 0);
    }

    k0 = knext;
    if (k0 >= K) break;
    __syncthreads();
  }

  const int lr4 = (l >> 4) * 4;
  const int lc  = l & 15;
#pragma unroll
  for (int m = 0; m < 4; ++m) {
    const int rbase = bm + wm + m * 16 + lr4;
#pragma unroll
    for (int n = 0; n < 4; ++n) {
      const int col = bn + wn + n * 16 + lc;
      const float bv = bias[col];
#pragma unroll
      for (int j = 0; j < 4; ++j) {
        const int r = rbase + j;
        if (r < M) C[(size_t)r * N + col] = acc[m][n][j] + bv;
      }
    }
  }
}

// ---------------------------------------------------------------------------
// Fused sampling-offset + attention-weight GEMM: logical N = 384, K = 256.
// ---------------------------------------------------------------------------
__global__ __launch_bounds__(256) void gemm_qoff_kernel(
    const float* __restrict__ A, const float* __restrict__ soW,
    const float* __restrict__ soB, const float* __restrict__ awW,
    const float* __restrict__ awB, float* __restrict__ offs,
    float* __restrict__ awr, int M) {
  __shared__ short As[128 * 64];
  __shared__ short Bs[128 * 64];

  const int t  = threadIdx.x;
  const int bm = blockIdx.y * 128;
  const int bn = blockIdx.x * 128;   // 0, 128, 256
  const int w  = t >> 6;
  const int l  = t & 63;
  const int wm = (w >> 1) * 64;
  const int wn = (w & 1) * 64;

  f32x4 acc[4][4];
#pragma unroll
  for (int m = 0; m < 4; ++m)
#pragma unroll
    for (int n = 0; n < 4; ++n) acc[m][n] = (f32x4){0.f, 0.f, 0.f, 0.f};

  float4 pa[8], pw[8];
  auto load_tile = [&](int k0) {
#pragma unroll
    for (int i = 0; i < 8; ++i) {
      const int slot = i * 256 + t;
      const int row  = slot >> 4;
      const int c4   = slot & 15;
      const int ar   = bm + row;
      pa[i] = (ar < M) ? *(const float4*)(A + (size_t)ar * 256 + k0 + c4 * 4)
                       : make_float4(0.f, 0.f, 0.f, 0.f);
      const int gn = bn + row;
      const float* Wp = (gn < 256) ? (soW + (size_t)gn * 256)
                                   : (awW + (size_t)(gn - 256) * 256);
      pw[i] = *(const float4*)(Wp + k0 + c4 * 4);
    }
  };

  load_tile(0);

  for (int k0 = 0;;) {
#pragma unroll
    for (int i = 0; i < 8; ++i) {
      const int slot = i * 256 + t;
      const int row  = slot >> 4;
      const int c4   = slot & 15;
      const int boff = (row * 128 + c4 * 8) ^ ((row & 7) << 4);
      uint2 ap;
      ap.x = cvt_pk_bf16(pa[i].x, pa[i].y);
      ap.y = cvt_pk_bf16(pa[i].z, pa[i].w);
      *(uint2*)((char*)As + boff) = ap;
      uint2 wp;
      wp.x = cvt_pk_bf16(pw[i].x, pw[i].y);
      wp.y = cvt_pk_bf16(pw[i].z, pw[i].w);
      *(uint2*)((char*)Bs + boff) = wp;
    }
    __syncthreads();

    const int knext = k0 + 64;
    if (knext < 256) load_tile(knext);

#pragma unroll
    for (int ks = 0; ks < 2; ++ks) {
      const int koff = (ks * 32 + (l >> 4) * 8) * 2;
      bf16x8 af[4], bfr[4];
#pragma unroll
      for (int m = 0; m < 4; ++m) {
        const int row = wm + m * 16 + (l & 15);
        af[m] = *(const bf16x8*)((const char*)As + ((row * 128 + koff) ^ ((row & 7) << 4)));
      }
#pragma unroll
      for (int n = 0; n < 4; ++n) {
        const int row = wn + n * 16 + (l & 15);
        bfr[n] = *(const bf16x8*)((const char*)Bs + ((row * 128 + koff) ^ ((row & 7) << 4)));
      }
#pragma unroll
      for (int m = 0; m < 4; ++m)
#pragma unroll
        for (int n = 0; n < 4; ++n)
          acc[m][n] = __builtin_amdgcn_mfma_f32_16x16x32_bf16(af[m], bfr[n], acc[m][n], 0, 0, 0);
    }

    k0 = knext;
    if (k0 >= 256) break;
    __syncthreads();
  }

  const int lr4 = (l >> 4) * 4;
  const int lc  = l & 15;
#pragma unroll
  for (int m = 0; m < 4; ++m) {
    const int rbase = bm + wm + m * 16 + lr4;
#pragma unroll
    for (int n = 0; n < 4; ++n) {
      const int col = bn + wn + n * 16 + lc;
      const float bv = (col < 256) ? soB[col] : awB[col - 256];
#pragma unroll
      for (int j = 0; j < 4; ++j) {
        const int r = rbase + j;
        if (r < M) {
          const float v = acc[m][n][j] + bv;
          if (col < 256) offs[(size_t)r * 256 + col] = v;
          else           awr[(size_t)r * 128 + col - 256] = v;
        }
      }
    }
  }
}

// ---------------------------------------------------------------------------
// bf16 MFMA flash self-attention, swapped-QK^T + max-free softmax. bf16 out.
// ---------------------------------------------------------------------------
__global__ __launch_bounds__(256) void self_attn_mfma_kernel(
    const unsigned short* __restrict__ qkv, unsigned short* __restrict__ out) {
  const int b = blockIdx.y >> 3;
  const int h = blockIdx.y & 7;
  const int t = threadIdx.x;
  const int w = t >> 6;
  const int l = t & 63;
  const int lr = l & 15;
  const int lc = l >> 4;

  __shared__ short Klds[64 * 40];
  __shared__ short Vt[32 * 68];
  __shared__ short Plds[4][2 * 16 * 68];

  const float scale = 0.17677669529663687f;
  const int qb0 = blockIdx.x * 128 + w * 16;

  bf16x8 qf[2] = {};
#pragma unroll
  for (int qt = 0; qt < 2; ++qt) {
    const int qr = qb0 + qt * 64 + lr;
    if (qr < kNQ)
      qf[qt] = *(const bf16x8*)(qkv + ((size_t)(b * kNQ + qr)) * 768 + h * 32 + lc * 8);
  }

  f32x4 o[2][2];
#pragma unroll
  for (int qt = 0; qt < 2; ++qt)
#pragma unroll
    for (int dh = 0; dh < 2; ++dh) o[qt][dh] = (f32x4){0.f, 0.f, 0.f, 0.f};
  const f32x4 zero4 = {0.f, 0.f, 0.f, 0.f};
  float lsum[2] = {0.f, 0.f};

  const int skey = t & 63, sc = t >> 6;
  bf16x8 kreg = {}, vreg = {};
  auto load_kv = [&](int tb) {
    const int kr = tb + skey;
    if (kr < kNQ) {
      const unsigned short* p = qkv + ((size_t)(b * kNQ + kr)) * 768 + h * 32 + sc * 8;
      kreg = *(const bf16x8*)(p + 256);
      vreg = *(const bf16x8*)(p + 512);
    } else {
      kreg = (bf16x8){}; vreg = (bf16x8){};
    }
  };

  load_kv(0);

  for (int tb = 0; tb < kNQ; tb += 64) {
    *(bf16x8*)&Klds[skey * 40 + sc * 8] = kreg;
#pragma unroll
    for (int i = 0; i < 8; ++i) Vt[(sc * 8 + i) * 68 + skey] = vreg[i];
    __syncthreads();

    if (tb + 64 < kNQ) load_kv(tb + 64);

    f32x4 s[2][4];
#pragma unroll
    for (int kt = 0; kt < 4; ++kt) {
      bf16x8 kf = *(const bf16x8*)&Klds[(kt * 16 + lr) * 40 + lc * 8];
      s[0][kt] = __builtin_amdgcn_mfma_f32_16x16x32_bf16(kf, qf[0], zero4, 0, 0, 0);
      s[1][kt] = __builtin_amdgcn_mfma_f32_16x16x32_bf16(kf, qf[1], zero4, 0, 0, 0);
    }

#pragma unroll
    for (int qt = 0; qt < 2; ++qt) {
      short* Pw = Plds[w] + qt * (16 * 68);
      float ls = 0.f;
#pragma unroll
      for (int kt = 0; kt < 4; ++kt) {
        float p[4];
#pragma unroll
        for (int j = 0; j < 4; ++j) {
          const int kg = tb + kt * 16 + lc * 4 + j;
          const float e = __expf(s[qt][kt][j] * scale);
          p[j] = (kg < kNQ) ? e : 0.f;
          ls += p[j];
        }
        uint2 pk;
        pk.x = cvt_pk_bf16(p[0], p[1]);
        pk.y = cvt_pk_bf16(p[2], p[3]);
        *(uint2*)&Pw[lr * 68 + kt * 16 + lc * 4] = pk;
      }
      lsum[qt] += ls;
    }

    bf16x8 v00 = *(const bf16x8*)&Vt[lr * 68 + lc * 8];
    bf16x8 v01 = *(const bf16x8*)&Vt[lr * 68 + 32 + lc * 8];
    bf16x8 v10 = *(const bf16x8*)&Vt[(16 + lr) * 68 + lc * 8];
    bf16x8 v11 = *(const bf16x8*)&Vt[(16 + lr) * 68 + 32 + lc * 8];
#pragma unroll
    for (int qt = 0; qt < 2; ++qt) {
      const short* Pw = Plds[w] + qt * (16 * 68);
      bf16x8 pa0 = *(const bf16x8*)&Pw[lr * 68 + lc * 8];
      bf16x8 pa1 = *(const bf16x8*)&Pw[lr * 68 + 32 + lc * 8];
      o[qt][0] = __builtin_amdgcn_mfma_f32_16x16x32_bf16(pa0, v00, o[qt][0], 0, 0, 0);
      o[qt][0] = __builtin_amdgcn_mfma_f32_16x16x32_bf16(pa1, v01, o[qt][0], 0, 0, 0);
      o[qt][1] = __builtin_amdgcn_mfma_f32_16x16x32_bf16(pa0, v10, o[qt][1], 0, 0, 0);
      o[qt][1] = __builtin_amdgcn_mfma_f32_16x16x32_bf16(pa1, v11, o[qt][1], 0, 0, 0);
    }
    __syncthreads();
  }

#pragma unroll
  for (int qt = 0; qt < 2; ++qt) {
    float lt = lsum[qt];
    lt += __shfl_xor(lt, 16);
    lt += __shfl_xor(lt, 32);
#pragma unroll
    for (int j = 0; j < 4; ++j) {
      const float lq = __shfl(lt, lc * 4 + j);
      const int q = qb0 + qt * 64 + lc * 4 + j;
      if (q < kNQ) {
        const float inv = 1.f / lq;
        unsigned short* op = out + ((size_t)(b * kNQ + q)) * 256 + h * 32;
        op[lr]      = f2bf(o[qt][0][j] * inv);
        op[16 + lr] = f2bf(o[qt][1][j] * inv);
      }
    }
  }
}

// ---------------------------------------------------------------------------
// out = LayerNorm(x + res) * g + b over rows of 256. One block per row.
// ---------------------------------------------------------------------------
__global__ __launch_bounds__(256) void ln_res_kernel(
    const float* __restrict__ x, const float* __restrict__ res,
    const float* __restrict__ g, const float* __restrict__ bta,
    float* __restrict__ out) {
  const int row = blockIdx.x;
  const int t = threadIdx.x;
  const size_t idx = (size_t)row * 256 + t;
  const float v = x[idx] + res[idx];
  float s = v, s2 = v * v;
#pragma unroll
  for (int mask = 1; mask < 64; mask <<= 1) {
    s  += __shfl_xor(s, mask);
    s2 += __shfl_xor(s2, mask);
  }
  __shared__ float ws[4], ws2[4];
  if ((t & 63) == 0) { ws[t >> 6] = s; ws2[t >> 6] = s2; }
  __syncthreads();
  const float S  = ws[0] + ws[1] + ws[2] + ws[3];
  const float S2 = ws2[0] + ws2[1] + ws2[2] + ws2[3];
  const float mean = S * (1.f / 256.f);
  const float var  = S2 * (1.f / 256.f) - mean * mean;
  const float rstd = rsqrtf(var + 1e-5f);
  out[idx] = (v - mean) * rstd * g[t] + bta[t];
}

// ---------------------------------------------------------------------------
// MS deformable attention, vectorized gather (r15 version). One block per
// (b,q). Thread: channel quad ch = (t&63)*4, wave = 4 samples of its head.
// ---------------------------------------------------------------------------
__global__ __launch_bounds__(256) void deform_kernel(
    const unsigned short* __restrict__ value,   // (B, LV, 256) bf16
    const float* __restrict__ offs,    // (B*NQ, 256)
    const float* __restrict__ awr,     // (B*NQ, 128)
    const float* __restrict__ refp,    // (B, NQ, 4, 2)
    unsigned short* __restrict__ out) {  // (B*NQ, 256) bf16
  const int bq = blockIdx.x;
  const int b = bq / kNQ;
  const int t = threadIdx.x;

  __shared__ int2  cpk[128][4];   // (idx, weight-bits) at pos = lp*8 + h
  __shared__ float part[4][256];  // per-wave channel partials

  if (t < 128) {
    const float a = awr[(size_t)bq * 128 + t];
    float mx = a;
#pragma unroll
    for (int mask = 1; mask < 16; mask <<= 1) mx = fmaxf(mx, __shfl_xor(mx, mask));
    const float e = __expf(a - mx);
    float se = e;
#pragma unroll
    for (int mask = 1; mask < 16; mask <<= 1) se += __shfl_xor(se, mask);
    const float aw = e / se;

    const int h = t >> 4, lp = t & 15, lvl = lp >> 2;
    const int HL[4] = {100, 50, 25, 13};
    const int WL[4] = {100, 50, 25, 13};
    const int ST[4] = {0, 10000, 12500, 13125};
    const int Hl = HL[lvl], Wl = WL[lvl], st = ST[lvl];
    const float rx = refp[((size_t)bq * 4 + lvl) * 2 + 0];
    const float ry = refp[((size_t)bq * 4 + lvl) * 2 + 1];
    const float ox = offs[(size_t)bq * 256 + h * 32 + lp * 2 + 0];
    const float oy = offs[(size_t)bq * 256 + h * 32 + lp * 2 + 1];
    const float x = rx * (float)Wl + ox - 0.5f;
    const float y = ry * (float)Hl + oy - 0.5f;
    const float x0f = floorf(x), y0f = floorf(y);
    const int x0 = (int)x0f, y0 = (int)y0f;
    const float lx = x - x0f, ly = y - y0f;
    const float wts[4] = {(1.f - lx) * (1.f - ly), lx * (1.f - ly),
                          (1.f - lx) * ly,         lx * ly};
    const int ys[4] = {y0, y0, y0 + 1, y0 + 1};
    const int xs[4] = {x0, x0 + 1, x0, x0 + 1};
    const int pos = lp * 8 + h;
#pragma unroll
    for (int c = 0; c < 4; ++c) {
      const int yy = ys[c], xx = xs[c];
      const bool valid = (yy >= 0) && (yy < Hl) && (xx >= 0) && (xx < Wl);
      const int yc = min(max(yy, 0), Hl - 1);
      const int xc = min(max(xx, 0), Wl - 1);
      const float wf = valid ? wts[c] * aw : 0.f;
      cpk[pos][c] = make_int2(st + yc * Wl + xc, __float_as_int(wf));
    }
  }
  __syncthreads();

  const int w  = t >> 6;       // wave: samples w*4 .. w*4+3
  const int q4 = t & 63;       // channel quad
  const int h  = q4 >> 3;      // head
  const int ch = q4 * 4;       // first channel of quad
  const unsigned short* vb = value + (size_t)b * kLV * 256 + ch;

  float a0 = 0.f, a1 = 0.f, a2 = 0.f, a3 = 0.f;
#pragma unroll
  for (int si = 0; si < 4; ++si) {
    const int s = w * 4 + si;
#pragma unroll
    for (int c = 0; c < 4; ++c) {
      const int2 p = cpk[s * 8 + h][c];
      const float wt = __int_as_float(p.y);
      const uint2 v = *(const uint2*)(vb + (size_t)p.x * 256);
      a0 = fmaf(wt, bf2f((unsigned short)(v.x & 0xffff)), a0);
      a1 = fmaf(wt, bf2f((unsigned short)(v.x >> 16)), a1);
      a2 = fmaf(wt, bf2f((unsigned short)(v.y & 0xffff)), a2);
      a3 = fmaf(wt, bf2f((unsigned short)(v.y >> 16)), a3);
    }
  }
  *(float4*)&part[w][ch] = make_float4(a0, a1, a2, a3);
  __syncthreads();

  out[(size_t)bq * 256 + t] = f2bf(part[0][t] + part[1][t] + part[2][t] + part[3][t]);
}

}  // namespace

extern "C" void kernel_launch(void* const* d_in, const int* in_sizes, int n_in,
                              void* d_out, int out_size, void* d_ws, size_t ws_size,
                              hipStream_t stream) {
  const float* query  = (const float*)d_in[0];
  const float* refp   = (const float*)d_in[1];
  const float* memory = (const float*)d_in[2];
  const float* in_w  = (const float*)d_in[6];
  const float* in_b  = (const float*)d_in[7];
  const float* out_w = (const float*)d_in[8];
  const float* out_b = (const float*)d_in[9];
  const float* ln1g  = (const float*)d_in[10];
  const float* ln1b  = (const float*)d_in[11];
  const float* vp_w  = (const float*)d_in[12];
  const float* vp_b  = (const float*)d_in[13];
  const float* so_w  = (const float*)d_in[14];
  const float* so_b  = (const float*)d_in[15];
  const float* aw_w  = (const float*)d_in[16];
  const float* aw_b  = (const float*)d_in[17];
  const float* ca_w  = (const float*)d_in[18];
  const float* ca_b  = (const float*)d_in[19];
  const float* ln2g  = (const float*)d_in[20];
  const float* ln2b  = (const float*)d_in[21];
  const float* f1_w  = (const float*)d_in[22];
  const float* f1_b  = (const float*)d_in[23];
  const float* f2_w  = (const float*)d_in[24];
  const float* f2_b  = (const float*)d_in[25];
  const float* ln3g  = (const float*)d_in[26];
  const float* ln3b  = (const float*)d_in[27];
  float* out = (float*)d_out;

  const int MQ = kB * kNQ;   // 7200
  const int MV = kB * kLV;   // 106352

  float* ws = (float*)d_ws;
  size_t o = 0;
  float* qkvr = ws;                             // region: qkv bf16 / ffh bf16
  o += (size_t)MQ * kDFF;
  float* sar  = ws + o;  o += (size_t)MQ * kD;  // sa bf16
  float* q1   = ws + o;  o += (size_t)MQ * kD;
  float* valr = ws + o;  o += (size_t)MV * kD;  // region: val_bf | m_bf (both bf16)
  float* offs = ws + o;  o += (size_t)MQ * kD;
  float* awr  = ws + o;  o += (size_t)MQ * 128;
  float* dfor = ws + o;  o += (size_t)MQ * kD;  // dfo bf16
  float* q2   = ws + o;  o += (size_t)MQ * kD;
  float* tmp  = ws + o;  o += (size_t)MQ * kD;
  (void)ws_size; (void)in_sizes; (void)n_in; (void)out_size;

  unsigned short* qkv_bf = (unsigned short*)qkvr;                         // MQ*768 bf16
  unsigned short* ffh_bf = (unsigned short*)qkvr;                         // MQ*1024 bf16 (qkv dead by then)
  unsigned short* sa_bf  = (unsigned short*)sar;                          // MQ*256 bf16
  unsigned short* dfo_bf = (unsigned short*)dfor;                         // MQ*256 bf16
  unsigned short* val_bf = (unsigned short*)valr;                         // MV*256 bf16
  unsigned short* m_bf   = (unsigned short*)(valr + (size_t)MV * kD / 2); // MV*256 bf16

  const dim3 blk(256);
  auto g128 = [](int M, int N) { return dim3((unsigned)((N + 127) / 128), (unsigned)((M + 127) / 128)); };

  // 0. memory -> bf16 (streaming)
  f32_to_bf16_kernel<<<2048, blk, 0, stream>>>(memory, (unsigned*)m_bf, MV * kD / 8);
  // 1. qkv = query @ in_proj^T + b  (bf16 out)
  gemm_mfma_kernel<<<g128(MQ, 768), blk, 0, stream>>>(query, in_w, in_b, qkv_bf, MQ, 768, kD, 0, 1);
  // 2. self-attention -> sa (bf16 out)
  self_attn_mfma_kernel<<<dim3((kNQ + 127) / 128, kB * 8), blk, 0, stream>>>(qkv_bf, sa_bf);
  // 3. out-proj (bf16 A) -> tmp
  gemm_mfma_bf16a_kernel<<<g128(MQ, kD), blk, 0, stream>>>(sa_bf, out_w, out_b, tmp, MQ, kD, kD);
  // 4. q1 = LN(query + tmp)
  ln_res_kernel<<<MQ, blk, 0, stream>>>(query, tmp, ln1g, ln1b, q1);
  // 5. value = m_bf @ value_proj^T + b  (persistent half-W, col-paired)
  gemm_val2_kernel<<<512, blk, 0, stream>>>(m_bf, vp_w, vp_b, val_bf, MV);
  // 6+7. fused sampling offsets + attention weights
  gemm_qoff_kernel<<<dim3(3, (MQ + 127) / 128), blk, 0, stream>>>(
      q1, so_w, so_b, aw_w, aw_b, offs, awr, MQ);
  // 8. deformable attention -> dfo (bf16 out)
  deform_kernel<<<MQ, blk, 0, stream>>>(val_bf, offs, awr, refp, dfo_bf);
  // 9. ca out-proj (bf16 A) -> tmp
  gemm_mfma_bf16a_kernel<<<g128(MQ, kD), blk, 0, stream>>>(dfo_bf, ca_w, ca_b, tmp, MQ, kD, kD);
  // 10. q2 = LN(q1 + tmp)
  ln_res_kernel<<<MQ, blk, 0, stream>>>(q1, tmp, ln2g, ln2b, q2);
  // 11. ffh = relu(q2 @ ffn_w1^T + b1)  (bf16 out)
  gemm_mfma_kernel<<<g128(MQ, kDFF), blk, 0, stream>>>(q2, f1_w, f1_b, ffh_bf, MQ, kDFF, kD, 1, 1);
  // 12. ffn2 (bf16 A, K=1024) -> tmp
  gemm_mfma_bf16a_kernel<<<g128(MQ, kD), blk, 0, stream>>>(ffh_bf, f2_w, f2_b, tmp, MQ, kD, kDFF);
  // 13. out = LN(q2 + tmp)
  ln_res_kernel<<<MQ, blk, 0, stream>>>(q2, tmp, ln3g, ln3b, out);
}

// Round 18
// 271.409 us; speedup vs baseline: 1.0963x; 1.0000x over previous
//
#include <hip/hip_runtime.h>
#include <cstddef>

namespace {

constexpr int kB   = 8;
constexpr int kNQ  = 900;
constexpr int kD   = 256;
constexpr int kDFF = 1024;
constexpr int kLV  = 13294;

typedef short bf16x8 __attribute__((ext_vector_type(8)));
typedef float f32x4  __attribute__((ext_vector_type(4)));

__device__ inline unsigned short f2bf(float f) {
  union { float f; unsigned u; } v; v.f = f;
  return (unsigned short)((v.u + 0x7FFF + ((v.u >> 16) & 1)) >> 16);
}

__device__ inline float bf2f(unsigned short u) {
  union { unsigned u; float f; } v; v.u = (unsigned)u << 16;
  return v.f;
}

// HW packed f32->bf16 (RNE)
__device__ inline unsigned cvt_pk_bf16(float a, float b) {
  unsigned r;
  asm("v_cvt_pk_bf16_f32 %0, %1, %2" : "=v"(r) : "v"(a), "v"(b));
  return r;
}

// ---------------------------------------------------------------------------
// Streaming f32 -> bf16 convert (8 floats / thread / iter).
// ---------------------------------------------------------------------------
__global__ __launch_bounds__(256) void f32_to_bf16_kernel(
    const float* __restrict__ in, unsigned* __restrict__ out, int n8) {
  int i = blockIdx.x * 256 + threadIdx.x;
  const int stride = gridDim.x * 256;
  for (; i < n8; i += stride) {
    const float4 a = ((const float4*)in)[(size_t)i * 2];
    const float4 b = ((const float4*)in)[(size_t)i * 2 + 1];
    uint4 r;
    r.x = cvt_pk_bf16(a.x, a.y);
    r.y = cvt_pk_bf16(a.z, a.w);
    r.z = cvt_pk_bf16(b.x, b.y);
    r.w = cvt_pk_bf16(b.z, b.w);
    ((uint4*)out)[i] = r;
  }
}

// ---------------------------------------------------------------------------
// Persistent value GEMM, 8-wave blocks: C_bf16[M,256] = A_bf16 @ W^T + bias.
// 512 threads/block, grid = 512 (2 col-halves x 256 slots), 2 blocks/CU ->
// 16 waves/CU (2x the r15 TLP) with the IDENTICAL per-wave inner loop:
// 32 A-fragment loads feed 128 MFMAs from the 64 KB XOR-swizzled W-half,
// zero barriers in the persistent loop. Per tile: 256 rows (4 wave-rows x 64).
// XCD col-pairing: blocks s and s+256 share s%8 -> same XCD L2 serves A.
// ---------------------------------------------------------------------------
__global__ __launch_bounds__(512, 2) void gemm_val2_kernel(
    const unsigned short* __restrict__ A, const float* __restrict__ W,
    const float* __restrict__ bias, unsigned short* __restrict__ C, int M) {
  __shared__ short Ws[128 * 256];   // 64 KB, row stride 512 B, XOR-swizzled

  const int t  = threadIdx.x;
  const int w  = t >> 6;            // 0..7
  const int l  = t & 63;
  const int lr = l & 15;
  const int lc = l >> 4;
  const int col  = (int)(blockIdx.x >> 8);   // 0 or 1
  const int slot = (int)(blockIdx.x & 255);
  const int bn = col * 128;
  const int wm = (w >> 1) * 64;     // 0,64,128,192
  const int wn = (w & 1) * 64;

  // ---- stage W-half once: 128 rows x 256 k, f32 -> bf16, swizzled ----
#pragma unroll 4
  for (int i = 0; i < 8; ++i) {
    const int idx = i * 512 + t;      // 4096 chunks of 8 floats
    const int row = idx >> 5;         // 32 chunks per row
    const int c16 = idx & 31;
    const float* wp = W + (size_t)(bn + row) * 256 + c16 * 8;
    const float4 w0 = *(const float4*)wp;
    const float4 w1 = *(const float4*)(wp + 4);
    uint4 p;
    p.x = cvt_pk_bf16(w0.x, w0.y);
    p.y = cvt_pk_bf16(w0.z, w0.w);
    p.z = cvt_pk_bf16(w1.x, w1.y);
    p.w = cvt_pk_bf16(w1.z, w1.w);
    const int boff = (row * 512 + c16 * 16) ^ ((row & 7) << 4);
    *(uint4*)((char*)Ws + boff) = p;
  }
  __syncthreads();

  float bv[4];
#pragma unroll
  for (int n = 0; n < 4; ++n) bv[n] = bias[bn + wn + n * 16 + lr];

  // ---- persistent loop over 256-row tiles, no barriers ----
  for (int tile = slot; tile * 256 < M; tile += 256) {
    const int bm = tile * 256;

    const unsigned short* apm[4];
#pragma unroll
    for (int m = 0; m < 4; ++m) {
      int row = bm + wm + m * 16 + lr;
      row = row < M ? row : M - 1;
      apm[m] = A + (size_t)row * 256 + lc * 8;
    }
    bf16x8 af[8][4];
#pragma unroll
    for (int kk = 0; kk < 8; ++kk)
#pragma unroll
      for (int m = 0; m < 4; ++m)
        af[kk][m] = *(const bf16x8*)(apm[m] + kk * 32);

    f32x4 acc[4][4];
#pragma unroll
    for (int m = 0; m < 4; ++m)
#pragma unroll
      for (int n = 0; n < 4; ++n) acc[m][n] = (f32x4){0.f, 0.f, 0.f, 0.f};

#pragma unroll
    for (int kk = 0; kk < 8; ++kk) {
      const int kb = kk * 64 + lc * 16;
      bf16x8 bfr[4];
#pragma unroll
      for (int n = 0; n < 4; ++n) {
        const int row = wn + n * 16 + lr;
        const int boff = (row * 512 + kb) ^ ((row & 7) << 4);
        bfr[n] = *(const bf16x8*)((const char*)Ws + boff);
      }
#pragma unroll
      for (int m = 0; m < 4; ++m)
#pragma unroll
        for (int n = 0; n < 4; ++n)
          acc[m][n] = __builtin_amdgcn_mfma_f32_16x16x32_bf16(af[kk][m], bfr[n], acc[m][n], 0, 0, 0);
    }

#pragma unroll
    for (int m = 0; m < 4; ++m) {
      const int rbase = bm + wm + m * 16 + lc * 4;
#pragma unroll
      for (int n = 0; n < 4; ++n) {
        const int cidx = bn + wn + n * 16 + lr;
#pragma unroll
        for (int j = 0; j < 4; ++j) {
          const int r = rbase + j;
          if (r < M) C[(size_t)r * 256 + cidx] = f2bf(acc[m][n][j] + bv[n]);
        }
      }
    }
  }
}

// ---------------------------------------------------------------------------
// Generic GEMM (f32 A): 128x128 tile, BK=64, reg-prefetch. Optional bf16 out.
// ---------------------------------------------------------------------------
__global__ __launch_bounds__(256) void gemm_mfma_kernel(
    const float* __restrict__ A, const float* __restrict__ W,
    const float* __restrict__ bias, void* __restrict__ Cv,
    int M, int N, int K, int relu, int out_bf16) {
  __shared__ short As[128 * 64];
  __shared__ short Bs[128 * 64];

  const int t  = threadIdx.x;
  const int bm = blockIdx.y * 128;
  const int bn = blockIdx.x * 128;
  const int w  = t >> 6;
  const int l  = t & 63;
  const int wm = (w >> 1) * 64;
  const int wn = (w & 1) * 64;

  f32x4 acc[4][4];
#pragma unroll
  for (int m = 0; m < 4; ++m)
#pragma unroll
    for (int n = 0; n < 4; ++n) acc[m][n] = (f32x4){0.f, 0.f, 0.f, 0.f};

  float4 pa[8], pw[8];
  auto load_tile = [&](int k0) {
#pragma unroll
    for (int i = 0; i < 8; ++i) {
      const int slot = i * 256 + t;
      const int row  = slot >> 4;
      const int c4   = slot & 15;
      const int ar   = bm + row;
      pa[i] = (ar < M) ? *(const float4*)(A + (size_t)ar * K + k0 + c4 * 4)
                       : make_float4(0.f, 0.f, 0.f, 0.f);
      pw[i] = *(const float4*)(W + (size_t)(bn + row) * K + k0 + c4 * 4);
    }
  };

  load_tile(0);

  for (int k0 = 0;;) {
#pragma unroll
    for (int i = 0; i < 8; ++i) {
      const int slot = i * 256 + t;
      const int row  = slot >> 4;
      const int c4   = slot & 15;
      const int boff = (row * 128 + c4 * 8) ^ ((row & 7) << 4);
      uint2 ap;
      ap.x = cvt_pk_bf16(pa[i].x, pa[i].y);
      ap.y = cvt_pk_bf16(pa[i].z, pa[i].w);
      *(uint2*)((char*)As + boff) = ap;
      uint2 wp;
      wp.x = cvt_pk_bf16(pw[i].x, pw[i].y);
      wp.y = cvt_pk_bf16(pw[i].z, pw[i].w);
      *(uint2*)((char*)Bs + boff) = wp;
    }
    __syncthreads();

    const int knext = k0 + 64;
    if (knext < K) load_tile(knext);

#pragma unroll
    for (int ks = 0; ks < 2; ++ks) {
      const int koff = (ks * 32 + (l >> 4) * 8) * 2;
      bf16x8 af[4], bfr[4];
#pragma unroll
      for (int m = 0; m < 4; ++m) {
        const int row = wm + m * 16 + (l & 15);
        af[m] = *(const bf16x8*)((const char*)As + ((row * 128 + koff) ^ ((row & 7) << 4)));
      }
#pragma unroll
      for (int n = 0; n < 4; ++n) {
        const int row = wn + n * 16 + (l & 15);
        bfr[n] = *(const bf16x8*)((const char*)Bs + ((row * 128 + koff) ^ ((row & 7) << 4)));
      }
#pragma unroll
      for (int m = 0; m < 4; ++m)
#pragma unroll
        for (int n = 0; n < 4; ++n)
          acc[m][n] = __builtin_amdgcn_mfma_f32_16x16x32_bf16(af[m], bfr[n], acc[m][n], 0, 0, 0);
    }

    k0 = knext;
    if (k0 >= K) break;
    __syncthreads();
  }

  const int lr4 = (l >> 4) * 4;
  const int lc  = l & 15;
#pragma unroll
  for (int m = 0; m < 4; ++m) {
    const int rbase = bm + wm + m * 16 + lr4;
#pragma unroll
    for (int n = 0; n < 4; ++n) {
      const int col = bn + wn + n * 16 + lc;
      const float bv = bias[col];
#pragma unroll
      for (int j = 0; j < 4; ++j) {
        const int r = rbase + j;
        if (r < M) {
          float v = acc[m][n][j] + bv;
          if (relu) v = fmaxf(v, 0.f);
          if (out_bf16)
            ((unsigned short*)Cv)[(size_t)r * N + col] = f2bf(v);
          else
            ((float*)Cv)[(size_t)r * N + col] = v;
        }
      }
    }
  }
}

// ---------------------------------------------------------------------------
// Generic GEMM, bf16 A: A staged as raw bf16 copies; W f32->bf16. f32 out.
// ---------------------------------------------------------------------------
__global__ __launch_bounds__(256) void gemm_mfma_bf16a_kernel(
    const unsigned short* __restrict__ A, const float* __restrict__ W,
    const float* __restrict__ bias, float* __restrict__ C,
    int M, int N, int K) {
  __shared__ short As[128 * 64];
  __shared__ short Bs[128 * 64];

  const int t  = threadIdx.x;
  const int bm = blockIdx.y * 128;
  const int bn = blockIdx.x * 128;
  const int w  = t >> 6;
  const int l  = t & 63;
  const int wm = (w >> 1) * 64;
  const int wn = (w & 1) * 64;

  f32x4 acc[4][4];
#pragma unroll
  for (int m = 0; m < 4; ++m)
#pragma unroll
    for (int n = 0; n < 4; ++n) acc[m][n] = (f32x4){0.f, 0.f, 0.f, 0.f};

  bf16x8 pa[4];
  float4 pw[8];
  auto load_tile = [&](int k0) {
#pragma unroll
    for (int i = 0; i < 4; ++i) {
      const int slot = i * 256 + t;        // 1024 chunks of 8 bf16
      const int row  = slot >> 3;
      const int c8   = slot & 7;
      int ar = bm + row;
      ar = ar < M ? ar : M - 1;
      pa[i] = *(const bf16x8*)(A + (size_t)ar * K + k0 + c8 * 8);
    }
#pragma unroll
    for (int i = 0; i < 8; ++i) {
      const int slot = i * 256 + t;
      const int row  = slot >> 4;
      const int c4   = slot & 15;
      pw[i] = *(const float4*)(W + (size_t)(bn + row) * K + k0 + c4 * 4);
    }
  };

  load_tile(0);

  for (int k0 = 0;;) {
#pragma unroll
    for (int i = 0; i < 4; ++i) {
      const int slot = i * 256 + t;
      const int row  = slot >> 3;
      const int c8   = slot & 7;
      const int boff = (row * 128 + c8 * 16) ^ ((row & 7) << 4);
      *(bf16x8*)((char*)As + boff) = pa[i];
    }
#pragma unroll
    for (int i = 0; i < 8; ++i) {
      const int slot = i * 256 + t;
      const int row  = slot >> 4;
      const int c4   = slot & 15;
      const int boff = (row * 128 + c4 * 8) ^ ((row & 7) << 4);
      uint2 wp;
      wp.x = cvt_pk_bf16(pw[i].x, pw[i].y);
      wp.y = cvt_pk_bf16(pw[i].z, pw[i].w);
      *(uint2*)((char*)Bs + boff) = wp;
    }
    __syncthreads();

    const int knext = k0 + 64;
    if (knext < K) load_tile(knext);

#pragma unroll
    for (int ks = 0; ks < 2; ++ks) {
      const int koff = (ks * 32 + (l >> 4) * 8) * 2;
      bf16x8 af[4], bfr[4];
#pragma unroll
      for (int m = 0; m < 4; ++m) {
        const int row = wm + m * 16 + (l & 15);
        af[m] = *(const bf16x8*)((const char*)As + ((row * 128 + koff) ^ ((row & 7) << 4)));
      }
#pragma unroll
      for (int n = 0; n < 4; ++n) {
        const int row = wn + n * 16 + (l & 15);
        bfr[n] = *(const bf16x8*)((const char*)Bs + ((row * 128 + koff) ^ ((row & 7) << 4)));
      }
#pragma unroll
      for (int m = 0; m < 4; ++m)
#pragma unroll
        for (int n = 0; n < 4; ++n)
          acc[m][n] = __builtin_amdgcn_mfma_f32_16x16x32_bf16(af[m], bfr[n], acc[m][n], 0, 0, 0);
    }

    k0 = knext;
    if (k0 >= K) break;
    __syncthreads();
  }

  const int lr4 = (l >> 4) * 4;
  const int lc  = l & 15;
#pragma unroll
  for (int m = 0; m < 4; ++m) {
    const int rbase = bm + wm + m * 16 + lr4;
#pragma unroll
    for (int n = 0; n < 4; ++n) {
      const int col = bn + wn + n * 16 + lc;
      const float bv = bias[col];
#pragma unroll
      for (int j = 0; j < 4; ++j) {
        const int r = rbase + j;
        if (r < M) C[(size_t)r * N + col] = acc[m][n][j] + bv;
      }
    }
  }
}

// ---------------------------------------------------------------------------
// Fused sampling-offset + attention-weight GEMM: logical N = 384, K = 256.
// ---------------------------------------------------------------------------
__global__ __launch_bounds__(256) void gemm_qoff_kernel(
    const float* __restrict__ A, const float* __restrict__ soW,
    const float* __restrict__ soB, const float* __restrict__ awW,
    const float* __restrict__ awB, float* __restrict__ offs,
    float* __restrict__ awr, int M) {
  __shared__ short As[128 * 64];
  __shared__ short Bs[128 * 64];

  const int t  = threadIdx.x;
  const int bm = blockIdx.y * 128;
  const int bn = blockIdx.x * 128;   // 0, 128, 256
  const int w  = t >> 6;
  const int l  = t & 63;
  const int wm = (w >> 1) * 64;
  const int wn = (w & 1) * 64;

  f32x4 acc[4][4];
#pragma unroll
  for (int m = 0; m < 4; ++m)
#pragma unroll
    for (int n = 0; n < 4; ++n) acc[m][n] = (f32x4){0.f, 0.f, 0.f, 0.f};

  float4 pa[8], pw[8];
  auto load_tile = [&](int k0) {
#pragma unroll
    for (int i = 0; i < 8; ++i) {
      const int slot = i * 256 + t;
      const int row  = slot >> 4;
      const int c4   = slot & 15;
      const int ar   = bm + row;
      pa[i] = (ar < M) ? *(const float4*)(A + (size_t)ar * 256 + k0 + c4 * 4)
                       : make_float4(0.f, 0.f, 0.f, 0.f);
      const int gn = bn + row;
      const float* Wp = (gn < 256) ? (soW + (size_t)gn * 256)
                                   : (awW + (size_t)(gn - 256) * 256);
      pw[i] = *(const float4*)(Wp + k0 + c4 * 4);
    }
  };

  load_tile(0);

  for (int k0 = 0;;) {
#pragma unroll
    for (int i = 0; i < 8; ++i) {
      const int slot = i * 256 + t;
      const int row  = slot >> 4;
      const int c4   = slot & 15;
      const int boff = (row * 128 + c4 * 8) ^ ((row & 7) << 4);
      uint2 ap;
      ap.x = cvt_pk_bf16(pa[i].x, pa[i].y);
      ap.y = cvt_pk_bf16(pa[i].z, pa[i].w);
      *(uint2*)((char*)As + boff) = ap;
      uint2 wp;
      wp.x = cvt_pk_bf16(pw[i].x, pw[i].y);
      wp.y = cvt_pk_bf16(pw[i].z, pw[i].w);
      *(uint2*)((char*)Bs + boff) = wp;
    }
    __syncthreads();

    const int knext = k0 + 64;
    if (knext < 256) load_tile(knext);

#pragma unroll
    for (int ks = 0; ks < 2; ++ks) {
      const int koff = (ks * 32 + (l >> 4) * 8) * 2;
      bf16x8 af[4], bfr[4];
#pragma unroll
      for (int m = 0; m < 4; ++m) {
        const int row = wm + m * 16 + (l & 15);
        af[m] = *(const bf16x8*)((const char*)As + ((row * 128 + koff) ^ ((row & 7) << 4)));
      }
#pragma unroll
      for (int n = 0; n < 4; ++n) {
        const int row = wn + n * 16 + (l & 15);
        bfr[n] = *(const bf16x8*)((const char*)Bs + ((row * 128 + koff) ^ ((row & 7) << 4)));
      }
#pragma unroll
      for (int m = 0; m < 4; ++m)
#pragma unroll
        for (int n = 0; n < 4; ++n)
          acc[m][n] = __builtin_amdgcn_mfma_f32_16x16x32_bf16(af[m], bfr[n], acc[m][n], 0, 0, 0);
    }

    k0 = knext;
    if (k0 >= 256) break;
    __syncthreads();
  }

  const int lr4 = (l >> 4) * 4;
  const int lc  = l & 15;
#pragma unroll
  for (int m = 0; m < 4; ++m) {
    const int rbase = bm + wm + m * 16 + lr4;
#pragma unroll
    for (int n = 0; n < 4; ++n) {
      const int col = bn + wn + n * 16 + lc;
      const float bv = (col < 256) ? soB[col] : awB[col - 256];
#pragma unroll
      for (int j = 0; j < 4; ++j) {
        const int r = rbase + j;
        if (r < M) {
          const float v = acc[m][n][j] + bv;
          if (col < 256) offs[(size_t)r * 256 + col] = v;
          else           awr[(size_t)r * 128 + col - 256] = v;
        }
      }
    }
  }
}

// ---------------------------------------------------------------------------
// bf16 MFMA flash self-attention, swapped-QK^T + max-free softmax. bf16 out.
// ---------------------------------------------------------------------------
__global__ __launch_bounds__(256) void self_attn_mfma_kernel(
    const unsigned short* __restrict__ qkv, unsigned short* __restrict__ out) {
  const int b = blockIdx.y >> 3;
  const int h = blockIdx.y & 7;
  const int t = threadIdx.x;
  const int w = t >> 6;
  const int l = t & 63;
  const int lr = l & 15;
  const int lc = l >> 4;

  __shared__ short Klds[64 * 40];
  __shared__ short Vt[32 * 68];
  __shared__ short Plds[4][2 * 16 * 68];

  const float scale = 0.17677669529663687f;
  const int qb0 = blockIdx.x * 128 + w * 16;

  bf16x8 qf[2] = {};
#pragma unroll
  for (int qt = 0; qt < 2; ++qt) {
    const int qr = qb0 + qt * 64 + lr;
    if (qr < kNQ)
      qf[qt] = *(const bf16x8*)(qkv + ((size_t)(b * kNQ + qr)) * 768 + h * 32 + lc * 8);
  }

  f32x4 o[2][2];
#pragma unroll
  for (int qt = 0; qt < 2; ++qt)
#pragma unroll
    for (int dh = 0; dh < 2; ++dh) o[qt][dh] = (f32x4){0.f, 0.f, 0.f, 0.f};
  const f32x4 zero4 = {0.f, 0.f, 0.f, 0.f};
  float lsum[2] = {0.f, 0.f};

  const int skey = t & 63, sc = t >> 6;
  bf16x8 kreg = {}, vreg = {};
  auto load_kv = [&](int tb) {
    const int kr = tb + skey;
    if (kr < kNQ) {
      const unsigned short* p = qkv + ((size_t)(b * kNQ + kr)) * 768 + h * 32 + sc * 8;
      kreg = *(const bf16x8*)(p + 256);
      vreg = *(const bf16x8*)(p + 512);
    } else {
      kreg = (bf16x8){}; vreg = (bf16x8){};
    }
  };

  load_kv(0);

  for (int tb = 0; tb < kNQ; tb += 64) {
    *(bf16x8*)&Klds[skey * 40 + sc * 8] = kreg;
#pragma unroll
    for (int i = 0; i < 8; ++i) Vt[(sc * 8 + i) * 68 + skey] = vreg[i];
    __syncthreads();

    if (tb + 64 < kNQ) load_kv(tb + 64);

    f32x4 s[2][4];
#pragma unroll
    for (int kt = 0; kt < 4; ++kt) {
      bf16x8 kf = *(const bf16x8*)&Klds[(kt * 16 + lr) * 40 + lc * 8];
      s[0][kt] = __builtin_amdgcn_mfma_f32_16x16x32_bf16(kf, qf[0], zero4, 0, 0, 0);
      s[1][kt] = __builtin_amdgcn_mfma_f32_16x16x32_bf16(kf, qf[1], zero4, 0, 0, 0);
    }

#pragma unroll
    for (int qt = 0; qt < 2; ++qt) {
      short* Pw = Plds[w] + qt * (16 * 68);
      float ls = 0.f;
#pragma unroll
      for (int kt = 0; kt < 4; ++kt) {
        float p[4];
#pragma unroll
        for (int j = 0; j < 4; ++j) {
          const int kg = tb + kt * 16 + lc * 4 + j;
          const float e = __expf(s[qt][kt][j] * scale);
          p[j] = (kg < kNQ) ? e : 0.f;
          ls += p[j];
        }
        uint2 pk;
        pk.x = cvt_pk_bf16(p[0], p[1]);
        pk.y = cvt_pk_bf16(p[2], p[3]);
        *(uint2*)&Pw[lr * 68 + kt * 16 + lc * 4] = pk;
      }
      lsum[qt] += ls;
    }

    bf16x8 v00 = *(const bf16x8*)&Vt[lr * 68 + lc * 8];
    bf16x8 v01 = *(const bf16x8*)&Vt[lr * 68 + 32 + lc * 8];
    bf16x8 v10 = *(const bf16x8*)&Vt[(16 + lr) * 68 + lc * 8];
    bf16x8 v11 = *(const bf16x8*)&Vt[(16 + lr) * 68 + 32 + lc * 8];
#pragma unroll
    for (int qt = 0; qt < 2; ++qt) {
      const short* Pw = Plds[w] + qt * (16 * 68);
      bf16x8 pa0 = *(const bf16x8*)&Pw[lr * 68 + lc * 8];
      bf16x8 pa1 = *(const bf16x8*)&Pw[lr * 68 + 32 + lc * 8];
      o[qt][0] = __builtin_amdgcn_mfma_f32_16x16x32_bf16(pa0, v00, o[qt][0], 0, 0, 0);
      o[qt][0] = __builtin_amdgcn_mfma_f32_16x16x32_bf16(pa1, v01, o[qt][0], 0, 0, 0);
      o[qt][1] = __builtin_amdgcn_mfma_f32_16x16x32_bf16(pa0, v10, o[qt][1], 0, 0, 0);
      o[qt][1] = __builtin_amdgcn_mfma_f32_16x16x32_bf16(pa1, v11, o[qt][1], 0, 0, 0);
    }
    __syncthreads();
  }

#pragma unroll
  for (int qt = 0; qt < 2; ++qt) {
    float lt = lsum[qt];
    lt += __shfl_xor(lt, 16);
    lt += __shfl_xor(lt, 32);
#pragma unroll
    for (int j = 0; j < 4; ++j) {
      const float lq = __shfl(lt, lc * 4 + j);
      const int q = qb0 + qt * 64 + lc * 4 + j;
      if (q < kNQ) {
        const float inv = 1.f / lq;
        unsigned short* op = out + ((size_t)(b * kNQ + q)) * 256 + h * 32;
        op[lr]      = f2bf(o[qt][0][j] * inv);
        op[16 + lr] = f2bf(o[qt][1][j] * inv);
      }
    }
  }
}

// ---------------------------------------------------------------------------
// out = LayerNorm(x + res) * g + b over rows of 256. One block per row.
// ---------------------------------------------------------------------------
__global__ __launch_bounds__(256) void ln_res_kernel(
    const float* __restrict__ x, const float* __restrict__ res,
    const float* __restrict__ g, const float* __restrict__ bta,
    float* __restrict__ out) {
  const int row = blockIdx.x;
  const int t = threadIdx.x;
  const size_t idx = (size_t)row * 256 + t;
  const float v = x[idx] + res[idx];
  float s = v, s2 = v * v;
#pragma unroll
  for (int mask = 1; mask < 64; mask <<= 1) {
    s  += __shfl_xor(s, mask);
    s2 += __shfl_xor(s2, mask);
  }
  __shared__ float ws[4], ws2[4];
  if ((t & 63) == 0) { ws[t >> 6] = s; ws2[t >> 6] = s2; }
  __syncthreads();
  const float S  = ws[0] + ws[1] + ws[2] + ws[3];
  const float S2 = ws2[0] + ws2[1] + ws2[2] + ws2[3];
  const float mean = S * (1.f / 256.f);
  const float var  = S2 * (1.f / 256.f) - mean * mean;
  const float rstd = rsqrtf(var + 1e-5f);
  out[idx] = (v - mean) * rstd * g[t] + bta[t];
}

// ---------------------------------------------------------------------------
// MS deformable attention, vectorized gather. One block per (b,q).
// ---------------------------------------------------------------------------
__global__ __launch_bounds__(256) void deform_kernel(
    const unsigned short* __restrict__ value,   // (B, LV, 256) bf16
    const float* __restrict__ offs,    // (B*NQ, 256)
    const float* __restrict__ awr,     // (B*NQ, 128)
    const float* __restrict__ refp,    // (B, NQ, 4, 2)
    unsigned short* __restrict__ out) {  // (B*NQ, 256) bf16
  const int bq = blockIdx.x;
  const int b = bq / kNQ;
  const int t = threadIdx.x;

  __shared__ int2  cpk[128][4];   // (idx, weight-bits) at pos = lp*8 + h
  __shared__ float part[4][256];  // per-wave channel partials

  if (t < 128) {
    const float a = awr[(size_t)bq * 128 + t];
    float mx = a;
#pragma unroll
    for (int mask = 1; mask < 16; mask <<= 1) mx = fmaxf(mx, __shfl_xor(mx, mask));
    const float e = __expf(a - mx);
    float se = e;
#pragma unroll
    for (int mask = 1; mask < 16; mask <<= 1) se += __shfl_xor(se, mask);
    const float aw = e / se;

    const int h = t >> 4, lp = t & 15, lvl = lp >> 2;
    const int HL[4] = {100, 50, 25, 13};
    const int WL[4] = {100, 50, 25, 13};
    const int ST[4] = {0, 10000, 12500, 13125};
    const int Hl = HL[lvl], Wl = WL[lvl], st = ST[lvl];
    const float rx = refp[((size_t)bq * 4 + lvl) * 2 + 0];
    const float ry = refp[((size_t)bq * 4 + lvl) * 2 + 1];
    const float ox = offs[(size_t)bq * 256 + h * 32 + lp * 2 + 0];
    const float oy = offs[(size_t)bq * 256 + h * 32 + lp * 2 + 1];
    const float x = rx * (float)Wl + ox - 0.5f;
    const float y = ry * (float)Hl + oy - 0.5f;
    const float x0f = floorf(x), y0f = floorf(y);
    const int x0 = (int)x0f, y0 = (int)y0f;
    const float lx = x - x0f, ly = y - y0f;
    const float wts[4] = {(1.f - lx) * (1.f - ly), lx * (1.f - ly),
                          (1.f - lx) * ly,         lx * ly};
    const int ys[4] = {y0, y0, y0 + 1, y0 + 1};
    const int xs[4] = {x0, x0 + 1, x0, x0 + 1};
    const int pos = lp * 8 + h;
#pragma unroll
    for (int c = 0; c < 4; ++c) {
      const int yy = ys[c], xx = xs[c];
      const bool valid = (yy >= 0) && (yy < Hl) && (xx >= 0) && (xx < Wl);
      const int yc = min(max(yy, 0), Hl - 1);
      const int xc = min(max(xx, 0), Wl - 1);
      const float wf = valid ? wts[c] * aw : 0.f;
      cpk[pos][c] = make_int2(st + yc * Wl + xc, __float_as_int(wf));
    }
  }
  __syncthreads();

  const int w  = t >> 6;       // wave: samples w*4 .. w*4+3
  const int q4 = t & 63;       // channel quad
  const int h  = q4 >> 3;      // head
  const int ch = q4 * 4;       // first channel of quad
  const unsigned short* vb = value + (size_t)b * kLV * 256 + ch;

  float a0 = 0.f, a1 = 0.f, a2 = 0.f, a3 = 0.f;
#pragma unroll
  for (int si = 0; si < 4; ++si) {
    const int s = w * 4 + si;
#pragma unroll
    for (int c = 0; c < 4; ++c) {
      const int2 p = cpk[s * 8 + h][c];
      const float wt = __int_as_float(p.y);
      const uint2 v = *(const uint2*)(vb + (size_t)p.x * 256);
      a0 = fmaf(wt, bf2f((unsigned short)(v.x & 0xffff)), a0);
      a1 = fmaf(wt, bf2f((unsigned short)(v.x >> 16)), a1);
      a2 = fmaf(wt, bf2f((unsigned short)(v.y & 0xffff)), a2);
      a3 = fmaf(wt, bf2f((unsigned short)(v.y >> 16)), a3);
    }
  }
  *(float4*)&part[w][ch] = make_float4(a0, a1, a2, a3);
  __syncthreads();

  out[(size_t)bq * 256 + t] = f2bf(part[0][t] + part[1][t] + part[2][t] + part[3][t]);
}

}  // namespace

extern "C" void kernel_launch(void* const* d_in, const int* in_sizes, int n_in,
                              void* d_out, int out_size, void* d_ws, size_t ws_size,
                              hipStream_t stream) {
  const float* query  = (const float*)d_in[0];
  const float* refp   = (const float*)d_in[1];
  const float* memory = (const float*)d_in[2];
  const float* in_w  = (const float*)d_in[6];
  const float* in_b  = (const float*)d_in[7];
  const float* out_w = (const float*)d_in[8];
  const float* out_b = (const float*)d_in[9];
  const float* ln1g  = (const float*)d_in[10];
  const float* ln1b  = (const float*)d_in[11];
  const float* vp_w  = (const float*)d_in[12];
  const float* vp_b  = (const float*)d_in[13];
  const float* so_w  = (const float*)d_in[14];
  const float* so_b  = (const float*)d_in[15];
  const float* aw_w  = (const float*)d_in[16];
  const float* aw_b  = (const float*)d_in[17];
  const float* ca_w  = (const float*)d_in[18];
  const float* ca_b  = (const float*)d_in[19];
  const float* ln2g  = (const float*)d_in[20];
  const float* ln2b  = (const float*)d_in[21];
  const float* f1_w  = (const float*)d_in[22];
  const float* f1_b  = (const float*)d_in[23];
  const float* f2_w  = (const float*)d_in[24];
  const float* f2_b  = (const float*)d_in[25];
  const float* ln3g  = (const float*)d_in[26];
  const float* ln3b  = (const float*)d_in[27];
  float* out = (float*)d_out;

  const int MQ = kB * kNQ;   // 7200
  const int MV = kB * kLV;   // 106352

  float* ws = (float*)d_ws;
  size_t o = 0;
  float* qkvr = ws;                             // region: qkv bf16 / ffh bf16
  o += (size_t)MQ * kDFF;
  float* sar  = ws + o;  o += (size_t)MQ * kD;  // sa bf16
  float* q1   = ws + o;  o += (size_t)MQ * kD;
  float* valr = ws + o;  o += (size_t)MV * kD;  // region: val_bf | m_bf (both bf16)
  float* offs = ws + o;  o += (size_t)MQ * kD;
  float* awr  = ws + o;  o += (size_t)MQ * 128;
  float* dfor = ws + o;  o += (size_t)MQ * kD;  // dfo bf16
  float* q2   = ws + o;  o += (size_t)MQ * kD;
  float* tmp  = ws + o;  o += (size_t)MQ * kD;
  (void)ws_size; (void)in_sizes; (void)n_in; (void)out_size;

  unsigned short* qkv_bf = (unsigned short*)qkvr;                         // MQ*768 bf16
  unsigned short* ffh_bf = (unsigned short*)qkvr;                         // MQ*1024 bf16 (qkv dead by then)
  unsigned short* sa_bf  = (unsigned short*)sar;                          // MQ*256 bf16
  unsigned short* dfo_bf = (unsigned short*)dfor;                         // MQ*256 bf16
  unsigned short* val_bf = (unsigned short*)valr;                         // MV*256 bf16
  unsigned short* m_bf   = (unsigned short*)(valr + (size_t)MV * kD / 2); // MV*256 bf16

  const dim3 blk(256);
  auto g128 = [](int M, int N) { return dim3((unsigned)((N + 127) / 128), (unsigned)((M + 127) / 128)); };

  // 0. memory -> bf16 (streaming)
  f32_to_bf16_kernel<<<2048, blk, 0, stream>>>(memory, (unsigned*)m_bf, MV * kD / 8);
  // 1. qkv = query @ in_proj^T + b  (bf16 out)
  gemm_mfma_kernel<<<g128(MQ, 768), blk, 0, stream>>>(query, in_w, in_b, qkv_bf, MQ, 768, kD, 0, 1);
  // 2. self-attention -> sa (bf16 out)
  self_attn_mfma_kernel<<<dim3((kNQ + 127) / 128, kB * 8), blk, 0, stream>>>(qkv_bf, sa_bf);
  // 3. out-proj (bf16 A) -> tmp
  gemm_mfma_bf16a_kernel<<<g128(MQ, kD), blk, 0, stream>>>(sa_bf, out_w, out_b, tmp, MQ, kD, kD);
  // 4. q1 = LN(query + tmp)
  ln_res_kernel<<<MQ, blk, 0, stream>>>(query, tmp, ln1g, ln1b, q1);
  // 5. value = m_bf @ value_proj^T + b  (persistent half-W, 8-wave blocks)
  gemm_val2_kernel<<<512, dim3(512), 0, stream>>>(m_bf, vp_w, vp_b, val_bf, MV);
  // 6+7. fused sampling offsets + attention weights
  gemm_qoff_kernel<<<dim3(3, (MQ + 127) / 128), blk, 0, stream>>>(
      q1, so_w, so_b, aw_w, aw_b, offs, awr, MQ);
  // 8. deformable attention -> dfo (bf16 out)
  deform_kernel<<<MQ, blk, 0, stream>>>(val_bf, offs, awr, refp, dfo_bf);
  // 9. ca out-proj (bf16 A) -> tmp
  gemm_mfma_bf16a_kernel<<<g128(MQ, kD), blk, 0, stream>>>(dfo_bf, ca_w, ca_b, tmp, MQ, kD, kD);
  // 10. q2 = LN(q1 + tmp)
  ln_res_kernel<<<MQ, blk, 0, stream>>>(q1, tmp, ln2g, ln2b, q2);
  // 11. ffh = relu(q2 @ ffn_w1^T + b1)  (bf16 out)
  gemm_mfma_kernel<<<g128(MQ, kDFF), blk, 0, stream>>>(q2, f1_w, f1_b, ffh_bf, MQ, kDFF, kD, 1, 1);
  // 12. ffn2 (bf16 A, K=1024) -> tmp
  gemm_mfma_bf16a_kernel<<<g128(MQ, kD), blk, 0, stream>>>(ffh_bf, f2_w, f2_b, tmp, MQ, kD, kDFF);
  // 13. out = LN(q2 + tmp)
  ln_res_kernel<<<MQ, blk, 0, stream>>>(q2, tmp, ln3g, ln3b, out);
}